// Round 3
// baseline (1261.602 us; speedup 1.0000x reference)
//
#include <hip/hip_runtime.h>
#include <hip/hip_bf16.h>
#include <math.h>

// ---------------------------------------------------------------------------
// TSRL fused forward, MFMA edition (round 7: 512-thread blocks, m-split).
// Round-6 post-mortem: pipelining+TT=64 gave -29% (MfmaUtil 13.6) but
// occupancy fell to 21% (2 blocks/CU, 2 waves/SIMD) -- still latency-bound,
// nothing saturated. This round keeps the tiling/pipelining and doubles
// waves/SIMD:
//  * 512-thread blocks (8 waves): wave = (mg = wv>>2, wg = wv&3).
//    wg keeps the oc split (80 or 16 cols); mg splits m into interleaved
//    16-row tiles (mt = mg + 2k). Per-wave MFMA work and registers halve
//    (worst acc[3][5]); __launch_bounds__(512,4) => <=128 regs, 2 blocks/CU
//    = 16 waves/CU = 4 waves/SIMD (2x round 6).
//  * L1/L2 B-fragments prefetched all-6 upfront (last unpipelined stalls).
//  * LDS 64112B: A[76][72] | Bf[76][72] (C[68][328] overlays Bf after L3);
//    pass-2: Rr[64][328]@0 (A,Bf,C dead), zb 8x[16][72]@41984 (C-tail dead),
//    XI/Gm/F2 static above zb.
// Masking per-m unchanged from round 6 (independent of wave assignment):
// L1 m<74, L2 m<72, L3 m<68, L4 exact 64.
// ---------------------------------------------------------------------------

#define BB    128
#define TSEQ  512
#define NTILE 8
#define DIN   12
#define C0    64
#define C1    320
#define TT    64
#define PP    76
#define HALO  6
#define R64P  72      // bf16 elems/row (144B = 36 dw == 4 mod 32)
#define R320P 328     // bf16 elems/row (656B = 164 dw == 4 mod 32)

#define S1 ((size_t)BB * TSEQ * C1)
#define S2 ((size_t)BB * TSEQ * DIN)

typedef __attribute__((ext_vector_type(8))) __bf16 bf16x8;
typedef __attribute__((ext_vector_type(4))) float f32x4;
#define MFMA16(a, b, c) __builtin_amdgcn_mfma_f32_16x16x32_bf16(a, b, c, 0, 0, 0)

// workspace (bf16 elem offsets): transposed bf16 weights Bt[n][k]
#define O01 0         // c01wT [64][192]
#define O02 12288     // c02wT [64][192]
#define O11 24576     // c11wT [320][192]
#define O12 86016     // c12wT [320][1024]  (k<960: conv taps; k>=960: c1_p 1x1)
#define OD  413696    // dwT   [1280][320]
#define OP  823296    // pwT   [16][1280]   (rows 12..15 zero)
#define NWS 843776    // weight elems
#define OGM 843776    // Gm fp32 [12][12] (288 bf16 elems)
#define OF2 844064    // F2 fp32 [12]     (24 elems)

// LDS byte offsets (64112 total => 2 blocks/CU, 16 waves/CU)
#define LA  0         // A: h0 raw -> h_b0 raw (T1)   [76][R64P] 10944
#define LB  10944     // Bf: gelu chain               [76][R64P] 10944
#define LC  10944     // C (TB1) overlays Bf post-L3  [68][R320P] -> ends 55552
#define LXI 60416     // x_interp fp32 [64][12] 3072 (static, above zb)
#define LGM 63488     // fc_w@fcr_w    [12][12] 576
#define LF2 64064     // fused bias    [12]     48
#define LSZ 64112
// pass-2 aliases (dead regions only):
#define LRR 0         // enc-out [64][R320P] bf16 = 41984 (A,Bf,C dead)
#define LZB 41984     // per-wave z chunk [16][R64P] bf16 = 2304 x 8 waves -> 60416

__device__ __forceinline__ float bf2f(const __hip_bfloat16 v) { return __bfloat162float(v); }
__device__ __forceinline__ __hip_bfloat16 f2bf(float f)       { return __float2bfloat16(f); }
__device__ __forceinline__ float geluf(float x) {
    return 0.5f * x * (1.0f + erff(x * 0.7071067811865475f));
}
__device__ __forceinline__ bf16x8 ldb8(const void* p) { return *(const bf16x8*)p; }

// ---- weight prep: fp32 -> bf16 transposed + Gm/F2, every launch ------------
extern "C" __global__ void __launch_bounds__(256) prep_w(
    const float* __restrict__ c01w, const float* __restrict__ c02w,
    const float* __restrict__ c11w, const float* __restrict__ c12w,
    const float* __restrict__ c1pw, const float* __restrict__ dw,
    const float* __restrict__ pw,
    const float* __restrict__ fcw,  const float* __restrict__ fcb,
    const float* __restrict__ fcrw, const float* __restrict__ fcrb,
    __hip_bfloat16* __restrict__ ws)
{
    for (size_t i = (size_t)blockIdx.x * 256 + threadIdx.x; i < NWS;
         i += (size_t)gridDim.x * 256) {
        float v;
        if (i < O02)      { int q = (int)i;        int n = q / 192, r = q % 192;
                            v = c01w[(n * 64 + (r & 63)) * 3 + (r >> 6)]; }
        else if (i < O11) { int q = (int)(i - O02); int n = q / 192, r = q % 192;
                            v = c02w[(n * 64 + (r & 63)) * 3 + (r >> 6)]; }
        else if (i < O12) { int q = (int)(i - O11); int n = q / 192, r = q % 192;
                            v = c11w[(n * 64 + (r & 63)) * 3 + (r >> 6)]; }
        else if (i < OD)  { int q = (int)(i - O12); int n = q >> 10, k = q & 1023;
                            v = (k < 960) ? c12w[(n * 320 + (k % 320)) * 3 + (k / 320)]
                                          : c1pw[n * 64 + (k - 960)]; }
        else if (i < OP)  { int q = (int)(i - OD);  int h = q / 320, c = q % 320;
                            v = dw[c * 1280 + h]; }
        else              { int q = (int)(i - OP);  int j = q / 1280, h = q % 1280;
                            v = (j < 12) ? pw[h * 12 + j] : 0.f; }
        ws[i] = f2bf(v);
    }
    if (blockIdx.x == 0) {
        float* gm = (float*)(ws + OGM);
        float* f2 = (float*)(ws + OF2);
        for (int o = threadIdx.x; o < 144; o += 256) {
            int j = o / 12, j2 = o - j * 12;
            float s = 0.f;
            for (int c = 0; c < C1; c++) s += fcw[j * C1 + c] * fcrw[c * 12 + j2];
            gm[o] = s;
        }
        if (threadIdx.x < 12) {
            float s = fcrb[threadIdx.x];
            for (int c = 0; c < C1; c++) s += fcb[c] * fcrw[c * 12 + threadIdx.x];
            f2[threadIdx.x] = s;
        }
    }
}

extern "C" __global__ void __launch_bounds__(512, 4) fused_main(
    const float* __restrict__ x1,  const float* __restrict__ X1,
    const float* __restrict__ X2,
    const float* __restrict__ w_in, const float* __restrict__ b_in,
    const float* __restrict__ c01b, const float* __restrict__ c02b,
    const float* __restrict__ c1pb, const float* __restrict__ c11b,
    const float* __restrict__ c12b,
    const float* __restrict__ db,   const float* __restrict__ pb,
    const __hip_bfloat16* __restrict__ ws,
    float* __restrict__ out)
{
    __shared__ __align__(16) unsigned char smem[LSZ];
    __hip_bfloat16* A  = (__hip_bfloat16*)(smem + LA);   // h0 -> T1
    __hip_bfloat16* Bf = (__hip_bfloat16*)(smem + LB);   // G0 -> T0 -> GH
    __hip_bfloat16* C  = (__hip_bfloat16*)(smem + LC);   // TB1 (rows p-4), overlays Bf
    float* XI = (float*)(smem + LXI);
    float* Gm = (float*)(smem + LGM);
    float* F2 = (float*)(smem + LF2);
    __hip_bfloat16* Rr = (__hip_bfloat16*)(smem + LRR);

    const int tid  = threadIdx.x;
    const int wv   = tid >> 6;
    const int wg   = wv & 3;           // oc-group (keeps column split)
    const int mg   = wv >> 2;          // m-group  (mt = mg + 2k interleave)
    const int lane = tid & 63;
    const int lm   = lane & 15;        // MFMA: A row / B col / D col
    const int lq   = lane >> 4;        // MFMA: k-octet / D row-quad
    const int bid  = blockIdx.x;
    const int pass = bid % 3;          // interleave heavy pass-2 blocks
    const int rem  = bid / 3;
    const int b    = rem >> 3;
    const int t0   = (rem & (NTILE - 1)) * TT;
    const float* xin = (pass == 0) ? X1 : (pass == 1) ? X2 : x1;

    const f32x4 Z4 = {0.f, 0.f, 0.f, 0.f};

    // ---- pass-2 prep: load Gm/F2 from ws, XI = ih_proj_b -------------------
    if (pass == 2) {
        const float* gmw = (const float*)(ws + OGM);
        const float* f2w = (const float*)(ws + OF2);
        for (int o = tid; o < 144; o += 512) Gm[o] = gmw[o];
        if (tid < 12) F2[tid] = f2w[tid];
        for (int o = tid; o < TT * 12; o += 512) XI[o] = pb[o % 12];
    }

    // ---- L0: x@w_in + b_in, rows [0,76) ------------------------------------
    for (int o = tid; o < PP * C0; o += 512) {
        int p = o >> 6, c = o & 63;
        int t = t0 + p - HALO;
        float acc = 0.f;
        if (t >= 0 && t < TSEQ) {
            acc = b_in[c];
            const float4* xr4 = (const float4*)(xin + ((size_t)b * TSEQ + t) * DIN);
            float4 v0 = xr4[0], v1 = xr4[1], v2 = xr4[2];
            const float xv[12] = {v0.x, v0.y, v0.z, v0.w, v1.x, v1.y,
                                  v1.z, v1.w, v2.x, v2.y, v2.z, v2.w};
            #pragma unroll
            for (int i = 0; i < DIN; i++) acc += xv[i] * w_in[i * C0 + c];
        }
        A [p * R64P + c] = f2bf(acc);
        Bf[p * R64P + c] = f2bf(geluf(acc));
    }
    __syncthreads();

    // ---- L1: conv0_1 64->64 k3 d1 on gelu(h0)=Bf, out rows [1,75) ----------
    {
        const int oc = wg * 16 + lm;
        bf16x8 bw[6];
        #pragma unroll
        for (int ks = 0; ks < 6; ks++)
            bw[ks] = ldb8(ws + O01 + oc * 192 + ks * 32 + (lq << 3));
        f32x4 acc[3] = {Z4, Z4, Z4};
        #pragma unroll
        for (int ks = 0; ks < 6; ks++) {
            int tap = ks >> 1, ci = ((ks & 1) << 5) + (lq << 3);
            #pragma unroll
            for (int kk = 0; kk < 3; kk++) {
                int mt = mg + 2 * kk;
                if (mt < 5) {
                    int p = 1 + mt * 16 + lm + tap - 1; p = p > 75 ? 75 : p;
                    acc[kk] = MFMA16(ldb8(Bf + p * R64P + ci), bw[ks], acc[kk]);
                }
            }
        }
        __syncthreads();   // all waves done reading G0 before in-place write
        float bias = c01b[oc];
        #pragma unroll
        for (int kk = 0; kk < 3; kk++) {
            int mt = mg + 2 * kk;
            if (mt < 5)
                #pragma unroll
                for (int r = 0; r < 4; r++) {
                    int m = mt * 16 + lq * 4 + r;
                    if (m < 74) {
                        int p = 1 + m, t = t0 + p - HALO;
                        Bf[p * R64P + oc] =
                            f2bf((t >= 0 && t < TSEQ) ? geluf(acc[kk][r] + bias) : 0.f);
                    }
                }
        }
    }
    __syncthreads();

    // ---- L2: conv0_2 on T0=Bf + residual h0=A, out rows [2,74) -------------
    {
        const int oc = wg * 16 + lm;
        bf16x8 bw[6];
        #pragma unroll
        for (int ks = 0; ks < 6; ks++)
            bw[ks] = ldb8(ws + O02 + oc * 192 + ks * 32 + (lq << 3));
        f32x4 acc[3] = {Z4, Z4, Z4};
        #pragma unroll
        for (int ks = 0; ks < 6; ks++) {
            int tap = ks >> 1, ci = ((ks & 1) << 5) + (lq << 3);
            #pragma unroll
            for (int kk = 0; kk < 3; kk++) {
                int mt = mg + 2 * kk;
                if (mt < 5) {
                    int p = 2 + mt * 16 + lm + tap - 1; p = p > 75 ? 75 : p;
                    acc[kk] = MFMA16(ldb8(Bf + p * R64P + ci), bw[ks], acc[kk]);
                }
            }
        }
        float resv[3][4];
        #pragma unroll
        for (int kk = 0; kk < 3; kk++) {
            int mt = mg + 2 * kk;
            #pragma unroll
            for (int r = 0; r < 4; r++) {
                int m = mt * 16 + lq * 4 + r;
                resv[kk][r] = (mt < 5 && m < 72) ? bf2f(A[(2 + m) * R64P + oc]) : 0.f;
            }
        }
        __syncthreads();   // reads of Bf and A complete
        float bias = c02b[oc];
        #pragma unroll
        for (int kk = 0; kk < 3; kk++) {
            int mt = mg + 2 * kk;
            if (mt < 5)
                #pragma unroll
                for (int r = 0; r < 4; r++) {
                    int m = mt * 16 + lq * 4 + r;
                    if (m < 72) {
                        int p = 2 + m, t = t0 + p - HALO;
                        bool v = (t >= 0 && t < TSEQ);
                        float hb = acc[kk][r] + bias + resv[kk][r];
                        A [p * R64P + oc] = f2bf(v ? hb : 0.f);          // T1 raw
                        Bf[p * R64P + oc] = f2bf(v ? geluf(hb) : 0.f);   // GH
                    }
                }
        }
    }
    __syncthreads();

    // ---- L3: c1_1 64->320 k3 d2 on GH=Bf, out rows [4,72) -> C[m<68] -------
    // B-fragment ping-pong prefetch; A-frags in-phase (LDS, covered by TLP).
    {
        f32x4 acc[3][5];
        #pragma unroll
        for (int kk = 0; kk < 3; kk++)
            #pragma unroll
            for (int nt = 0; nt < 5; nt++) acc[kk][nt] = Z4;
        bf16x8 bcur[5], bnxt[5];
        #pragma unroll
        for (int nt = 0; nt < 5; nt++)
            bcur[nt] = ldb8(ws + O11 + (wg * 80 + nt * 16 + lm) * 192 + (lq << 3));
        #pragma unroll
        for (int ks = 0; ks < 6; ks++) {
            if (ks < 5)
                #pragma unroll
                for (int nt = 0; nt < 5; nt++)
                    bnxt[nt] = ldb8(ws + O11 + (wg * 80 + nt * 16 + lm) * 192
                                    + (ks + 1) * 32 + (lq << 3));
            int tap = ks >> 1, ci = ((ks & 1) << 5) + (lq << 3);
            bf16x8 a[3];
            #pragma unroll
            for (int kk = 0; kk < 3; kk++) {
                int mt = mg + 2 * kk;
                if (mt < 5) {
                    int p = 4 + mt * 16 + lm + 2 * (tap - 1); p = p > 75 ? 75 : p;
                    a[kk] = ldb8(Bf + p * R64P + ci);
                }
            }
            #pragma unroll
            for (int nt = 0; nt < 5; nt++)
                #pragma unroll
                for (int kk = 0; kk < 3; kk++)
                    if (mg + 2 * kk < 5)
                        acc[kk][nt] = MFMA16(a[kk], bcur[nt], acc[kk][nt]);
            #pragma unroll
            for (int nt = 0; nt < 5; nt++) bcur[nt] = bnxt[nt];
        }
        __syncthreads();   // all waves done reading Bf before C overlays it
        #pragma unroll
        for (int nt = 0; nt < 5; nt++) {
            int oc = wg * 80 + nt * 16 + lm;
            float bias = c11b[oc];
            #pragma unroll
            for (int kk = 0; kk < 3; kk++) {
                int mt = mg + 2 * kk;
                if (mt < 5)
                    #pragma unroll
                    for (int r = 0; r < 4; r++) {
                        int m = mt * 16 + lq * 4 + r;
                        if (m < 68) {
                            int t = t0 + 4 + m - HALO;
                            C[m * R320P + oc] =
                                f2bf((t >= 0 && t < TSEQ) ? geluf(acc[kk][nt][r] + bias) : 0.f);
                        }
                    }
            }
        }
    }
    __syncthreads();

    // ---- L4: c1_2 320->320 k3 d2 (K=960) + c1_p 1x1 on T1=A (K=64) ---------
    // out rows [6,70) == 64 exactly (no mask). Full even/odd A+B pipeline.
    {
        f32x4 acc[2][5];
        #pragma unroll
        for (int kk = 0; kk < 2; kk++)
            #pragma unroll
            for (int nt = 0; nt < 5; nt++) acc[kk][nt] = Z4;
        bf16x8 aa[2], ba[5], ab[2], bb[5];
        auto ld4 = [&](int ks, bf16x8 (&a)[2], bf16x8 (&bw)[5]) {
            if (ks < 30) {
                int tap = (ks >= 20) ? 2 : (ks >= 10 ? 1 : 0);
                int ci = (ks - tap * 10) * 32 + (lq << 3);
                #pragma unroll
                for (int kk = 0; kk < 2; kk++) {
                    int mt = mg + 2 * kk;
                    a[kk] = ldb8(C + (2 + mt * 16 + lm + 2 * (tap - 1)) * R320P + ci);
                }
            } else {
                int ci = ((ks - 30) << 5) + (lq << 3);
                #pragma unroll
                for (int kk = 0; kk < 2; kk++) {
                    int mt = mg + 2 * kk;
                    a[kk] = ldb8(A + (6 + mt * 16 + lm) * R64P + ci);
                }
            }
            #pragma unroll
            for (int nt = 0; nt < 5; nt++)
                bw[nt] = ldb8(ws + O12 + (wg * 80 + nt * 16 + lm) * 1024
                              + ks * 32 + (lq << 3));
        };
        ld4(0, aa, ba);
        for (int ks = 0; ks < 32; ks += 2) {
            ld4(ks + 1, ab, bb);
            #pragma unroll
            for (int nt = 0; nt < 5; nt++)
                #pragma unroll
                for (int kk = 0; kk < 2; kk++)
                    acc[kk][nt] = MFMA16(aa[kk], ba[nt], acc[kk][nt]);
            if (ks + 2 < 32) ld4(ks + 2, aa, ba);
            #pragma unroll
            for (int nt = 0; nt < 5; nt++)
                #pragma unroll
                for (int kk = 0; kk < 2; kk++)
                    acc[kk][nt] = MFMA16(ab[kk], bb[nt], acc[kk][nt]);
        }
        if (pass < 2) {
            #pragma unroll
            for (int nt = 0; nt < 5; nt++) {
                int oc = wg * 80 + nt * 16 + lm;
                float bias = c12b[oc] + c1pb[oc];
                const size_t obase = (pass == 1) ? S1 : (size_t)0;
                #pragma unroll
                for (int kk = 0; kk < 2; kk++) {
                    int mt = mg + 2 * kk;
                    #pragma unroll
                    for (int r = 0; r < 4; r++) {
                        int m = mt * 16 + lq * 4 + r;
                        out[obase + ((size_t)b * TSEQ + t0 + m) * C1 + oc] =
                            acc[kk][nt][r] + bias;
                    }
                }
            }
        } else {
            __syncthreads();   // all waves done reading C,A -> safe to alias Rr
            #pragma unroll
            for (int nt = 0; nt < 5; nt++) {
                int oc = wg * 80 + nt * 16 + lm;
                float bias = c12b[oc] + c1pb[oc];
                #pragma unroll
                for (int kk = 0; kk < 2; kk++) {
                    int mt = mg + 2 * kk;
                    #pragma unroll
                    for (int r = 0; r < 4; r++) {
                        int m = mt * 16 + lq * 4 + r;
                        Rr[m * R320P + oc] = f2bf(acc[kk][nt][r] + bias);
                    }
                }
            }
            __syncthreads();   // Rr complete (cross-wave K in dense stage)
        }
    }

    // ---- pass-2: dense 320->1280, relu, @pw (MFMA), @Gm, outputs -----------
    if (pass == 2) {
        __hip_bfloat16* zb = (__hip_bfloat16*)(smem + LZB) + wv * (16 * R64P);
        f32x4 xacc[2] = {Z4, Z4};
        for (int cn = 0; cn < 5; cn++) {
            const int h0 = wg * 320 + cn * 64;
            f32x4 dacc[2][4];
            #pragma unroll
            for (int kk = 0; kk < 2; kk++)
                #pragma unroll
                for (int nt = 0; nt < 4; nt++) dacc[kk][nt] = Z4;
            bf16x8 aa[2], ba[4], ab[2], bb[4];
            auto ldd = [&](int ks, bf16x8 (&a)[2], bf16x8 (&bw)[4]) {
                int ci = ks * 32 + (lq << 3);
                #pragma unroll
                for (int kk = 0; kk < 2; kk++)
                    a[kk] = ldb8(Rr + ((mg + 2 * kk) * 16 + lm) * R320P + ci);
                #pragma unroll
                for (int nt = 0; nt < 4; nt++)
                    bw[nt] = ldb8(ws + OD + (h0 + nt * 16 + lm) * 320 + ci);
            };
            ldd(0, aa, ba);
            #pragma unroll
            for (int ks = 0; ks < 10; ks += 2) {
                ldd(ks + 1, ab, bb);
                #pragma unroll
                for (int nt = 0; nt < 4; nt++)
                    #pragma unroll
                    for (int kk = 0; kk < 2; kk++)
                        dacc[kk][nt] = MFMA16(aa[kk], ba[nt], dacc[kk][nt]);
                if (ks + 2 < 10) ldd(ks + 2, aa, ba);
                #pragma unroll
                for (int nt = 0; nt < 4; nt++)
                    #pragma unroll
                    for (int kk = 0; kk < 2; kk++)
                        dacc[kk][nt] = MFMA16(ab[kk], bb[nt], dacc[kk][nt]);
            }
            // per-kk: relu -> zb (wave-private, DS in-order) -> proj MFMA
            #pragma unroll
            for (int kk = 0; kk < 2; kk++) {
                #pragma unroll
                for (int nt = 0; nt < 4; nt++) {
                    int h = h0 + nt * 16 + lm;
                    float dbv = db[h];
                    #pragma unroll
                    for (int r = 0; r < 4; r++)
                        zb[(lq * 4 + r) * R64P + nt * 16 + lm] =
                            f2bf(fmaxf(dacc[kk][nt][r] + dbv, 0.f));
                }
                #pragma unroll
                for (int k2 = 0; k2 < 2; k2++) {
                    int hl = k2 * 32 + (lq << 3);
                    bf16x8 bf = ldb8(ws + OP + lm * 1280 + h0 + hl);
                    xacc[kk] = MFMA16(ldb8(zb + lm * R64P + hl), bf, xacc[kk]);
                }
            }
        }
        if (lm < 12) {
            #pragma unroll
            for (int kk = 0; kk < 2; kk++) {
                int mt = mg + 2 * kk;
                #pragma unroll
                for (int r = 0; r < 4; r++)
                    atomicAdd(&XI[(mt * 16 + lq * 4 + r) * 12 + lm], xacc[kk][r]);
            }
        }
        __syncthreads();
        for (int o = tid; o < TT * 12; o += 512) {
            int p = o / 12, j2 = o - p * 12;
            float val = F2[j2];
            #pragma unroll
            for (int j = 0; j < 12; j++) val += XI[p * 12 + j] * Gm[j * 12 + j2];
            size_t idx = ((size_t)b * TSEQ + t0 + p) * DIN + j2;
            out[2 * S1 + idx]      = val;   // outputs1
            out[2 * S1 + S2 + idx] = val;   // outputs2 (ref uses y_t1 for both)
        }
    }
}

// ---- masks + passthrough: m1, m2, x1, x2 -----------------------------------
extern "C" __global__ void __launch_bounds__(256) tail_kernel(
    const float* __restrict__ x1, const float* __restrict__ x2,
    float* __restrict__ out)
{
    size_t i = (size_t)blockIdx.x * 256 + threadIdx.x;
    if (i >= S2) return;
    float a = x1[i], c = x2[i];
    const size_t base = 2 * S1 + 2 * S2;
    out[base + i]          = (a != 0.f) ? 1.f : 0.f;
    out[base + S2 + i]     = (c != 0.f) ? 1.f : 0.f;
    out[base + 2 * S2 + i] = a;
    out[base + 3 * S2 + i] = c;
}

extern "C" void kernel_launch(void* const* d_in, const int* in_sizes, int n_in,
                              void* d_out, int out_size, void* d_ws, size_t ws_size,
                              hipStream_t stream)
{
    (void)in_sizes; (void)n_in; (void)ws_size; (void)out_size;
    const float* x1   = (const float*)d_in[0];
    const float* x2   = (const float*)d_in[1];
    const float* X1   = (const float*)d_in[2];
    const float* X2   = (const float*)d_in[3];
    const float* w_in = (const float*)d_in[5];
    const float* b_in = (const float*)d_in[6];
    const float* c01w = (const float*)d_in[7];
    const float* c01b = (const float*)d_in[8];
    const float* c02w = (const float*)d_in[9];
    const float* c02b = (const float*)d_in[10];
    const float* c1pw = (const float*)d_in[11];
    const float* c1pb = (const float*)d_in[12];
    const float* c11w = (const float*)d_in[13];
    const float* c11b = (const float*)d_in[14];
    const float* c12w = (const float*)d_in[15];
    const float* c12b = (const float*)d_in[16];
    const float* dwp  = (const float*)d_in[17];
    const float* dbp  = (const float*)d_in[18];
    const float* pwp  = (const float*)d_in[19];
    const float* pbp  = (const float*)d_in[20];
    const float* fcw  = (const float*)d_in[21];
    const float* fcb  = (const float*)d_in[22];
    const float* fcrw = (const float*)d_in[29];
    const float* fcrb = (const float*)d_in[30];
    float* out = (float*)d_out;
    __hip_bfloat16* ws = (__hip_bfloat16*)d_ws;

    prep_w<<<824, 256, 0, stream>>>(c01w, c02w, c11w, c12w, c1pw, dwp, pwp,
                                    fcw, fcb, fcrw, fcrb, ws);

    fused_main<<<3 * BB * NTILE, 512, 0, stream>>>(
        x1, X1, X2, w_in, b_in, c01b, c02b, c1pb, c11b, c12b,
        dbp, pbp, ws, out);

    tail_kernel<<<(int)((S2 + 255) / 256), 256, 0, stream>>>(x1, x2, out);
}

// Round 4
// 1257.312 us; speedup vs baseline: 1.0034x; 1.0034x over previous
//
#include <hip/hip_runtime.h>
#include <hip/hip_bf16.h>
#include <math.h>

// ---------------------------------------------------------------------------
// TSRL fused forward, MFMA edition (round 8: fix round-7 spills).
// Round-7 post-mortem: __launch_bounds__(512,4) forced VGPR=64 -> massive
// scratch spills (FETCH 26->79GB, WRITE 170->357GB), dur 700->1082us even
// though occupancy hit 41%. Structure (512-thread m-split) was fine; the
// register budget wasn't. This round: identical structure with
// __launch_bounds__(512,2) -> VGPR cap >=128 (2 blocks/CU, 16 waves/CU),
// which fits the ~90-115-reg per-wave working set. Everything else is the
// round-6/7 lineage:
//  * wave = (mg = wv>>2, wg = wv&3); mg splits m into interleaved 16-row
//    tiles, wg keeps the oc split. Per-wave MFMA work/registers halved
//    vs the 256-thread round-6 version.
//  * TT=64 (PP=76), even/odd pipelined L4/dense loops, upfront B-frags in
//    L1/L2, ping-pong B in L3.
//  * LDS 64112B: A[76][72] | Bf[76][72] (C[68][328] overlays Bf post-L3);
//    pass-2 aliases: Rr[64][328]@0, zb 8x[16][72]@41984, XI/Gm/F2 static.
// Masking: L1 m<74, L2 m<72, L3 m<68, L4 exact 64 (re-derived round 6).
// ---------------------------------------------------------------------------

#define BB    128
#define TSEQ  512
#define NTILE 8
#define DIN   12
#define C0    64
#define C1    320
#define TT    64
#define PP    76
#define HALO  6
#define R64P  72      // bf16 elems/row (144B = 36 dw == 4 mod 32)
#define R320P 328     // bf16 elems/row (656B = 164 dw == 4 mod 32)

#define S1 ((size_t)BB * TSEQ * C1)
#define S2 ((size_t)BB * TSEQ * DIN)

typedef __attribute__((ext_vector_type(8))) __bf16 bf16x8;
typedef __attribute__((ext_vector_type(4))) float f32x4;
#define MFMA16(a, b, c) __builtin_amdgcn_mfma_f32_16x16x32_bf16(a, b, c, 0, 0, 0)

// workspace (bf16 elem offsets): transposed bf16 weights Bt[n][k]
#define O01 0         // c01wT [64][192]
#define O02 12288     // c02wT [64][192]
#define O11 24576     // c11wT [320][192]
#define O12 86016     // c12wT [320][1024]  (k<960: conv taps; k>=960: c1_p 1x1)
#define OD  413696    // dwT   [1280][320]
#define OP  823296    // pwT   [16][1280]   (rows 12..15 zero)
#define NWS 843776    // weight elems
#define OGM 843776    // Gm fp32 [12][12] (288 bf16 elems)
#define OF2 844064    // F2 fp32 [12]     (24 elems)

// LDS byte offsets (64112 total => 2 blocks/CU, 16 waves/CU)
#define LA  0         // A: h0 raw -> h_b0 raw (T1)   [76][R64P] 10944
#define LB  10944     // Bf: gelu chain               [76][R64P] 10944
#define LC  10944     // C (TB1) overlays Bf post-L3  [68][R320P] -> ends 55552
#define LXI 60416     // x_interp fp32 [64][12] 3072 (static, above zb)
#define LGM 63488     // fc_w@fcr_w    [12][12] 576
#define LF2 64064     // fused bias    [12]     48
#define LSZ 64112
// pass-2 aliases (dead regions only):
#define LRR 0         // enc-out [64][R320P] bf16 = 41984 (A,Bf,C dead)
#define LZB 41984     // per-wave z chunk [16][R64P] bf16 = 2304 x 8 waves -> 60416

__device__ __forceinline__ float bf2f(const __hip_bfloat16 v) { return __bfloat162float(v); }
__device__ __forceinline__ __hip_bfloat16 f2bf(float f)       { return __float2bfloat16(f); }
__device__ __forceinline__ float geluf(float x) {
    return 0.5f * x * (1.0f + erff(x * 0.7071067811865475f));
}
__device__ __forceinline__ bf16x8 ldb8(const void* p) { return *(const bf16x8*)p; }

// ---- weight prep: fp32 -> bf16 transposed + Gm/F2, every launch ------------
extern "C" __global__ void __launch_bounds__(256) prep_w(
    const float* __restrict__ c01w, const float* __restrict__ c02w,
    const float* __restrict__ c11w, const float* __restrict__ c12w,
    const float* __restrict__ c1pw, const float* __restrict__ dw,
    const float* __restrict__ pw,
    const float* __restrict__ fcw,  const float* __restrict__ fcb,
    const float* __restrict__ fcrw, const float* __restrict__ fcrb,
    __hip_bfloat16* __restrict__ ws)
{
    for (size_t i = (size_t)blockIdx.x * 256 + threadIdx.x; i < NWS;
         i += (size_t)gridDim.x * 256) {
        float v;
        if (i < O02)      { int q = (int)i;        int n = q / 192, r = q % 192;
                            v = c01w[(n * 64 + (r & 63)) * 3 + (r >> 6)]; }
        else if (i < O11) { int q = (int)(i - O02); int n = q / 192, r = q % 192;
                            v = c02w[(n * 64 + (r & 63)) * 3 + (r >> 6)]; }
        else if (i < O12) { int q = (int)(i - O11); int n = q / 192, r = q % 192;
                            v = c11w[(n * 64 + (r & 63)) * 3 + (r >> 6)]; }
        else if (i < OD)  { int q = (int)(i - O12); int n = q >> 10, k = q & 1023;
                            v = (k < 960) ? c12w[(n * 320 + (k % 320)) * 3 + (k / 320)]
                                          : c1pw[n * 64 + (k - 960)]; }
        else if (i < OP)  { int q = (int)(i - OD);  int h = q / 320, c = q % 320;
                            v = dw[c * 1280 + h]; }
        else              { int q = (int)(i - OP);  int j = q / 1280, h = q % 1280;
                            v = (j < 12) ? pw[h * 12 + j] : 0.f; }
        ws[i] = f2bf(v);
    }
    if (blockIdx.x == 0) {
        float* gm = (float*)(ws + OGM);
        float* f2 = (float*)(ws + OF2);
        for (int o = threadIdx.x; o < 144; o += 256) {
            int j = o / 12, j2 = o - j * 12;
            float s = 0.f;
            for (int c = 0; c < C1; c++) s += fcw[j * C1 + c] * fcrw[c * 12 + j2];
            gm[o] = s;
        }
        if (threadIdx.x < 12) {
            float s = fcrb[threadIdx.x];
            for (int c = 0; c < C1; c++) s += fcb[c] * fcrw[c * 12 + threadIdx.x];
            f2[threadIdx.x] = s;
        }
    }
}

extern "C" __global__ void __launch_bounds__(512, 2) fused_main(
    const float* __restrict__ x1,  const float* __restrict__ X1,
    const float* __restrict__ X2,
    const float* __restrict__ w_in, const float* __restrict__ b_in,
    const float* __restrict__ c01b, const float* __restrict__ c02b,
    const float* __restrict__ c1pb, const float* __restrict__ c11b,
    const float* __restrict__ c12b,
    const float* __restrict__ db,   const float* __restrict__ pb,
    const __hip_bfloat16* __restrict__ ws,
    float* __restrict__ out)
{
    __shared__ __align__(16) unsigned char smem[LSZ];
    __hip_bfloat16* A  = (__hip_bfloat16*)(smem + LA);   // h0 -> T1
    __hip_bfloat16* Bf = (__hip_bfloat16*)(smem + LB);   // G0 -> T0 -> GH
    __hip_bfloat16* C  = (__hip_bfloat16*)(smem + LC);   // TB1 (rows p-4), overlays Bf
    float* XI = (float*)(smem + LXI);
    float* Gm = (float*)(smem + LGM);
    float* F2 = (float*)(smem + LF2);
    __hip_bfloat16* Rr = (__hip_bfloat16*)(smem + LRR);

    const int tid  = threadIdx.x;
    const int wv   = tid >> 6;
    const int wg   = wv & 3;           // oc-group (keeps column split)
    const int mg   = wv >> 2;          // m-group  (mt = mg + 2k interleave)
    const int lane = tid & 63;
    const int lm   = lane & 15;        // MFMA: A row / B col / D col
    const int lq   = lane >> 4;        // MFMA: k-octet / D row-quad
    const int bid  = blockIdx.x;
    const int pass = bid % 3;          // interleave heavy pass-2 blocks
    const int rem  = bid / 3;
    const int b    = rem >> 3;
    const int t0   = (rem & (NTILE - 1)) * TT;
    const float* xin = (pass == 0) ? X1 : (pass == 1) ? X2 : x1;

    const f32x4 Z4 = {0.f, 0.f, 0.f, 0.f};

    // ---- pass-2 prep: load Gm/F2 from ws, XI = ih_proj_b -------------------
    if (pass == 2) {
        const float* gmw = (const float*)(ws + OGM);
        const float* f2w = (const float*)(ws + OF2);
        for (int o = tid; o < 144; o += 512) Gm[o] = gmw[o];
        if (tid < 12) F2[tid] = f2w[tid];
        for (int o = tid; o < TT * 12; o += 512) XI[o] = pb[o % 12];
    }

    // ---- L0: x@w_in + b_in, rows [0,76) ------------------------------------
    for (int o = tid; o < PP * C0; o += 512) {
        int p = o >> 6, c = o & 63;
        int t = t0 + p - HALO;
        float acc = 0.f;
        if (t >= 0 && t < TSEQ) {
            acc = b_in[c];
            const float4* xr4 = (const float4*)(xin + ((size_t)b * TSEQ + t) * DIN);
            float4 v0 = xr4[0], v1 = xr4[1], v2 = xr4[2];
            const float xv[12] = {v0.x, v0.y, v0.z, v0.w, v1.x, v1.y,
                                  v1.z, v1.w, v2.x, v2.y, v2.z, v2.w};
            #pragma unroll
            for (int i = 0; i < DIN; i++) acc += xv[i] * w_in[i * C0 + c];
        }
        A [p * R64P + c] = f2bf(acc);
        Bf[p * R64P + c] = f2bf(geluf(acc));
    }
    __syncthreads();

    // ---- L1: conv0_1 64->64 k3 d1 on gelu(h0)=Bf, out rows [1,75) ----------
    {
        const int oc = wg * 16 + lm;
        bf16x8 bw[6];
        #pragma unroll
        for (int ks = 0; ks < 6; ks++)
            bw[ks] = ldb8(ws + O01 + oc * 192 + ks * 32 + (lq << 3));
        f32x4 acc[3] = {Z4, Z4, Z4};
        #pragma unroll
        for (int ks = 0; ks < 6; ks++) {
            int tap = ks >> 1, ci = ((ks & 1) << 5) + (lq << 3);
            #pragma unroll
            for (int kk = 0; kk < 3; kk++) {
                int mt = mg + 2 * kk;
                if (mt < 5) {
                    int p = 1 + mt * 16 + lm + tap - 1; p = p > 75 ? 75 : p;
                    acc[kk] = MFMA16(ldb8(Bf + p * R64P + ci), bw[ks], acc[kk]);
                }
            }
        }
        __syncthreads();   // all waves done reading G0 before in-place write
        float bias = c01b[oc];
        #pragma unroll
        for (int kk = 0; kk < 3; kk++) {
            int mt = mg + 2 * kk;
            if (mt < 5)
                #pragma unroll
                for (int r = 0; r < 4; r++) {
                    int m = mt * 16 + lq * 4 + r;
                    if (m < 74) {
                        int p = 1 + m, t = t0 + p - HALO;
                        Bf[p * R64P + oc] =
                            f2bf((t >= 0 && t < TSEQ) ? geluf(acc[kk][r] + bias) : 0.f);
                    }
                }
        }
    }
    __syncthreads();

    // ---- L2: conv0_2 on T0=Bf + residual h0=A, out rows [2,74) -------------
    {
        const int oc = wg * 16 + lm;
        bf16x8 bw[6];
        #pragma unroll
        for (int ks = 0; ks < 6; ks++)
            bw[ks] = ldb8(ws + O02 + oc * 192 + ks * 32 + (lq << 3));
        f32x4 acc[3] = {Z4, Z4, Z4};
        #pragma unroll
        for (int ks = 0; ks < 6; ks++) {
            int tap = ks >> 1, ci = ((ks & 1) << 5) + (lq << 3);
            #pragma unroll
            for (int kk = 0; kk < 3; kk++) {
                int mt = mg + 2 * kk;
                if (mt < 5) {
                    int p = 2 + mt * 16 + lm + tap - 1; p = p > 75 ? 75 : p;
                    acc[kk] = MFMA16(ldb8(Bf + p * R64P + ci), bw[ks], acc[kk]);
                }
            }
        }
        float resv[3][4];
        #pragma unroll
        for (int kk = 0; kk < 3; kk++) {
            int mt = mg + 2 * kk;
            #pragma unroll
            for (int r = 0; r < 4; r++) {
                int m = mt * 16 + lq * 4 + r;
                resv[kk][r] = (mt < 5 && m < 72) ? bf2f(A[(2 + m) * R64P + oc]) : 0.f;
            }
        }
        __syncthreads();   // reads of Bf and A complete
        float bias = c02b[oc];
        #pragma unroll
        for (int kk = 0; kk < 3; kk++) {
            int mt = mg + 2 * kk;
            if (mt < 5)
                #pragma unroll
                for (int r = 0; r < 4; r++) {
                    int m = mt * 16 + lq * 4 + r;
                    if (m < 72) {
                        int p = 2 + m, t = t0 + p - HALO;
                        bool v = (t >= 0 && t < TSEQ);
                        float hb = acc[kk][r] + bias + resv[kk][r];
                        A [p * R64P + oc] = f2bf(v ? hb : 0.f);          // T1 raw
                        Bf[p * R64P + oc] = f2bf(v ? geluf(hb) : 0.f);   // GH
                    }
                }
        }
    }
    __syncthreads();

    // ---- L3: c1_1 64->320 k3 d2 on GH=Bf, out rows [4,72) -> C[m<68] -------
    // B-fragment ping-pong prefetch; A-frags in-phase (LDS, covered by TLP).
    {
        f32x4 acc[3][5];
        #pragma unroll
        for (int kk = 0; kk < 3; kk++)
            #pragma unroll
            for (int nt = 0; nt < 5; nt++) acc[kk][nt] = Z4;
        bf16x8 bcur[5], bnxt[5];
        #pragma unroll
        for (int nt = 0; nt < 5; nt++)
            bcur[nt] = ldb8(ws + O11 + (wg * 80 + nt * 16 + lm) * 192 + (lq << 3));
        #pragma unroll
        for (int ks = 0; ks < 6; ks++) {
            if (ks < 5)
                #pragma unroll
                for (int nt = 0; nt < 5; nt++)
                    bnxt[nt] = ldb8(ws + O11 + (wg * 80 + nt * 16 + lm) * 192
                                    + (ks + 1) * 32 + (lq << 3));
            int tap = ks >> 1, ci = ((ks & 1) << 5) + (lq << 3);
            bf16x8 a[3];
            #pragma unroll
            for (int kk = 0; kk < 3; kk++) {
                int mt = mg + 2 * kk;
                if (mt < 5) {
                    int p = 4 + mt * 16 + lm + 2 * (tap - 1); p = p > 75 ? 75 : p;
                    a[kk] = ldb8(Bf + p * R64P + ci);
                }
            }
            #pragma unroll
            for (int nt = 0; nt < 5; nt++)
                #pragma unroll
                for (int kk = 0; kk < 3; kk++)
                    if (mg + 2 * kk < 5)
                        acc[kk][nt] = MFMA16(a[kk], bcur[nt], acc[kk][nt]);
            #pragma unroll
            for (int nt = 0; nt < 5; nt++) bcur[nt] = bnxt[nt];
        }
        __syncthreads();   // all waves done reading Bf before C overlays it
        #pragma unroll
        for (int nt = 0; nt < 5; nt++) {
            int oc = wg * 80 + nt * 16 + lm;
            float bias = c11b[oc];
            #pragma unroll
            for (int kk = 0; kk < 3; kk++) {
                int mt = mg + 2 * kk;
                if (mt < 5)
                    #pragma unroll
                    for (int r = 0; r < 4; r++) {
                        int m = mt * 16 + lq * 4 + r;
                        if (m < 68) {
                            int t = t0 + 4 + m - HALO;
                            C[m * R320P + oc] =
                                f2bf((t >= 0 && t < TSEQ) ? geluf(acc[kk][nt][r] + bias) : 0.f);
                        }
                    }
            }
        }
    }
    __syncthreads();

    // ---- L4: c1_2 320->320 k3 d2 (K=960) + c1_p 1x1 on T1=A (K=64) ---------
    // out rows [6,70) == 64 exactly (no mask). Full even/odd A+B pipeline.
    {
        f32x4 acc[2][5];
        #pragma unroll
        for (int kk = 0; kk < 2; kk++)
            #pragma unroll
            for (int nt = 0; nt < 5; nt++) acc[kk][nt] = Z4;
        bf16x8 aa[2], ba[5], ab[2], bb[5];
        auto ld4 = [&](int ks, bf16x8 (&a)[2], bf16x8 (&bw)[5]) {
            if (ks < 30) {
                int tap = (ks >= 20) ? 2 : (ks >= 10 ? 1 : 0);
                int ci = (ks - tap * 10) * 32 + (lq << 3);
                #pragma unroll
                for (int kk = 0; kk < 2; kk++) {
                    int mt = mg + 2 * kk;
                    a[kk] = ldb8(C + (2 + mt * 16 + lm + 2 * (tap - 1)) * R320P + ci);
                }
            } else {
                int ci = ((ks - 30) << 5) + (lq << 3);
                #pragma unroll
                for (int kk = 0; kk < 2; kk++) {
                    int mt = mg + 2 * kk;
                    a[kk] = ldb8(A + (6 + mt * 16 + lm) * R64P + ci);
                }
            }
            #pragma unroll
            for (int nt = 0; nt < 5; nt++)
                bw[nt] = ldb8(ws + O12 + (wg * 80 + nt * 16 + lm) * 1024
                              + ks * 32 + (lq << 3));
        };
        ld4(0, aa, ba);
        for (int ks = 0; ks < 32; ks += 2) {
            ld4(ks + 1, ab, bb);
            #pragma unroll
            for (int nt = 0; nt < 5; nt++)
                #pragma unroll
                for (int kk = 0; kk < 2; kk++)
                    acc[kk][nt] = MFMA16(aa[kk], ba[nt], acc[kk][nt]);
            if (ks + 2 < 32) ld4(ks + 2, aa, ba);
            #pragma unroll
            for (int nt = 0; nt < 5; nt++)
                #pragma unroll
                for (int kk = 0; kk < 2; kk++)
                    acc[kk][nt] = MFMA16(ab[kk], bb[nt], acc[kk][nt]);
        }
        if (pass < 2) {
            #pragma unroll
            for (int nt = 0; nt < 5; nt++) {
                int oc = wg * 80 + nt * 16 + lm;
                float bias = c12b[oc] + c1pb[oc];
                const size_t obase = (pass == 1) ? S1 : (size_t)0;
                #pragma unroll
                for (int kk = 0; kk < 2; kk++) {
                    int mt = mg + 2 * kk;
                    #pragma unroll
                    for (int r = 0; r < 4; r++) {
                        int m = mt * 16 + lq * 4 + r;
                        out[obase + ((size_t)b * TSEQ + t0 + m) * C1 + oc] =
                            acc[kk][nt][r] + bias;
                    }
                }
            }
        } else {
            __syncthreads();   // all waves done reading C,A -> safe to alias Rr
            #pragma unroll
            for (int nt = 0; nt < 5; nt++) {
                int oc = wg * 80 + nt * 16 + lm;
                float bias = c12b[oc] + c1pb[oc];
                #pragma unroll
                for (int kk = 0; kk < 2; kk++) {
                    int mt = mg + 2 * kk;
                    #pragma unroll
                    for (int r = 0; r < 4; r++) {
                        int m = mt * 16 + lq * 4 + r;
                        Rr[m * R320P + oc] = f2bf(acc[kk][nt][r] + bias);
                    }
                }
            }
            __syncthreads();   // Rr complete (cross-wave K in dense stage)
        }
    }

    // ---- pass-2: dense 320->1280, relu, @pw (MFMA), @Gm, outputs -----------
    if (pass == 2) {
        __hip_bfloat16* zb = (__hip_bfloat16*)(smem + LZB) + wv * (16 * R64P);
        f32x4 xacc[2] = {Z4, Z4};
        for (int cn = 0; cn < 5; cn++) {
            const int h0 = wg * 320 + cn * 64;
            f32x4 dacc[2][4];
            #pragma unroll
            for (int kk = 0; kk < 2; kk++)
                #pragma unroll
                for (int nt = 0; nt < 4; nt++) dacc[kk][nt] = Z4;
            bf16x8 aa[2], ba[4], ab[2], bb[4];
            auto ldd = [&](int ks, bf16x8 (&a)[2], bf16x8 (&bw)[4]) {
                int ci = ks * 32 + (lq << 3);
                #pragma unroll
                for (int kk = 0; kk < 2; kk++)
                    a[kk] = ldb8(Rr + ((mg + 2 * kk) * 16 + lm) * R320P + ci);
                #pragma unroll
                for (int nt = 0; nt < 4; nt++)
                    bw[nt] = ldb8(ws + OD + (h0 + nt * 16 + lm) * 320 + ci);
            };
            ldd(0, aa, ba);
            #pragma unroll
            for (int ks = 0; ks < 10; ks += 2) {
                ldd(ks + 1, ab, bb);
                #pragma unroll
                for (int nt = 0; nt < 4; nt++)
                    #pragma unroll
                    for (int kk = 0; kk < 2; kk++)
                        dacc[kk][nt] = MFMA16(aa[kk], ba[nt], dacc[kk][nt]);
                if (ks + 2 < 10) ldd(ks + 2, aa, ba);
                #pragma unroll
                for (int nt = 0; nt < 4; nt++)
                    #pragma unroll
                    for (int kk = 0; kk < 2; kk++)
                        dacc[kk][nt] = MFMA16(ab[kk], bb[nt], dacc[kk][nt]);
            }
            // per-kk: relu -> zb (wave-private, DS in-order) -> proj MFMA
            #pragma unroll
            for (int kk = 0; kk < 2; kk++) {
                #pragma unroll
                for (int nt = 0; nt < 4; nt++) {
                    int h = h0 + nt * 16 + lm;
                    float dbv = db[h];
                    #pragma unroll
                    for (int r = 0; r < 4; r++)
                        zb[(lq * 4 + r) * R64P + nt * 16 + lm] =
                            f2bf(fmaxf(dacc[kk][nt][r] + dbv, 0.f));
                }
                #pragma unroll
                for (int k2 = 0; k2 < 2; k2++) {
                    int hl = k2 * 32 + (lq << 3);
                    bf16x8 bf = ldb8(ws + OP + lm * 1280 + h0 + hl);
                    xacc[kk] = MFMA16(ldb8(zb + lm * R64P + hl), bf, xacc[kk]);
                }
            }
        }
        if (lm < 12) {
            #pragma unroll
            for (int kk = 0; kk < 2; kk++) {
                int mt = mg + 2 * kk;
                #pragma unroll
                for (int r = 0; r < 4; r++)
                    atomicAdd(&XI[(mt * 16 + lq * 4 + r) * 12 + lm], xacc[kk][r]);
            }
        }
        __syncthreads();
        for (int o = tid; o < TT * 12; o += 512) {
            int p = o / 12, j2 = o - p * 12;
            float val = F2[j2];
            #pragma unroll
            for (int j = 0; j < 12; j++) val += XI[p * 12 + j] * Gm[j * 12 + j2];
            size_t idx = ((size_t)b * TSEQ + t0 + p) * DIN + j2;
            out[2 * S1 + idx]      = val;   // outputs1
            out[2 * S1 + S2 + idx] = val;   // outputs2 (ref uses y_t1 for both)
        }
    }
}

// ---- masks + passthrough: m1, m2, x1, x2 -----------------------------------
extern "C" __global__ void __launch_bounds__(256) tail_kernel(
    const float* __restrict__ x1, const float* __restrict__ x2,
    float* __restrict__ out)
{
    size_t i = (size_t)blockIdx.x * 256 + threadIdx.x;
    if (i >= S2) return;
    float a = x1[i], c = x2[i];
    const size_t base = 2 * S1 + 2 * S2;
    out[base + i]          = (a != 0.f) ? 1.f : 0.f;
    out[base + S2 + i]     = (c != 0.f) ? 1.f : 0.f;
    out[base + 2 * S2 + i] = a;
    out[base + 3 * S2 + i] = c;
}

extern "C" void kernel_launch(void* const* d_in, const int* in_sizes, int n_in,
                              void* d_out, int out_size, void* d_ws, size_t ws_size,
                              hipStream_t stream)
{
    (void)in_sizes; (void)n_in; (void)ws_size; (void)out_size;
    const float* x1   = (const float*)d_in[0];
    const float* x2   = (const float*)d_in[1];
    const float* X1   = (const float*)d_in[2];
    const float* X2   = (const float*)d_in[3];
    const float* w_in = (const float*)d_in[5];
    const float* b_in = (const float*)d_in[6];
    const float* c01w = (const float*)d_in[7];
    const float* c01b = (const float*)d_in[8];
    const float* c02w = (const float*)d_in[9];
    const float* c02b = (const float*)d_in[10];
    const float* c1pw = (const float*)d_in[11];
    const float* c1pb = (const float*)d_in[12];
    const float* c11w = (const float*)d_in[13];
    const float* c11b = (const float*)d_in[14];
    const float* c12w = (const float*)d_in[15];
    const float* c12b = (const float*)d_in[16];
    const float* dwp  = (const float*)d_in[17];
    const float* dbp  = (const float*)d_in[18];
    const float* pwp  = (const float*)d_in[19];
    const float* pbp  = (const float*)d_in[20];
    const float* fcw  = (const float*)d_in[21];
    const float* fcb  = (const float*)d_in[22];
    const float* fcrw = (const float*)d_in[29];
    const float* fcrb = (const float*)d_in[30];
    float* out = (float*)d_out;
    __hip_bfloat16* ws = (__hip_bfloat16*)d_ws;

    prep_w<<<824, 256, 0, stream>>>(c01w, c02w, c11w, c12w, c1pw, dwp, pwp,
                                    fcw, fcb, fcrw, fcrb, ws);

    fused_main<<<3 * BB * NTILE, 512, 0, stream>>>(
        x1, X1, X2, w_in, b_in, c01b, c02b, c1pb, c11b, c12b,
        dbp, pbp, ws, out);

    tail_kernel<<<(int)((S2 + 255) / 256), 256, 0, stream>>>(x1, x2, out);
}

// Round 5
// 933.900 us; speedup vs baseline: 1.3509x; 1.3463x over previous
//
#include <hip/hip_runtime.h>
#include <hip/hip_bf16.h>
#include <math.h>

// ---------------------------------------------------------------------------
// TSRL fused forward, MFMA edition (round 9: 3 blocks/CU via LDS+reg diet).
// Round-8 forensics: rocprof VGPR_Count EXCLUDES accum regs (unified file).
// Occupancy steps on total (arch+accum): r6 116+~100=216 -> 2 waves/SIMD;
// r7 64+64=128 -> 4; r8 80+60=140 -> 2. 512-thr m-split also intrinsically
// slower than 256-thr at equal waves/CU (1066 vs 700) -> revert to 256-thr
// round-6 structure (700us) and lift waves/SIMD 2->3:
//  * LDS 59248 -> 54176 (3 blocks/CU): C/Rr stored [.][320] with XOR swizzle
//    (byte ^= (row&7)<<4) replacing pad-328 (also kills 16-way b128 read
//    conflicts); A trimmed to 74 live rows; XI/Gm/F2 moved into pass-2 alias
//    region (init after L4 when C dead).
//  * Regs <= 170 total: __launch_bounds__(256,3); L3 un-pipelined
//    (acc[5][5]=100 accum, arch ~50), L4/dense keep B-only ping-pong.
// Masking per round 6: L1 m<74, L2 m<72, L3 m<68, L4 exact 64.
// ---------------------------------------------------------------------------

#define BB    128
#define TSEQ  512
#define NTILE 8
#define DIN   12
#define C0    64
#define C1    320
#define TT    64
#define PP    76
#define HALO  6
#define R64P  72      // bf16 elems/row (144B = 36 dw == 4 mod 32)

#define S1 ((size_t)BB * TSEQ * C1)
#define S2 ((size_t)BB * TSEQ * DIN)

typedef __attribute__((ext_vector_type(8))) __bf16 bf16x8;
typedef __attribute__((ext_vector_type(4))) float f32x4;
#define MFMA16(a, b, c) __builtin_amdgcn_mfma_f32_16x16x32_bf16(a, b, c, 0, 0, 0)

// workspace (bf16 elem offsets): transposed bf16 weights Bt[n][k]
#define O01 0         // c01wT [64][192]
#define O02 12288     // c02wT [64][192]
#define O11 24576     // c11wT [320][192]
#define O12 86016     // c12wT [320][1024]  (k<960: conv taps; k>=960: c1_p 1x1)
#define OD  413696    // dwT   [1280][320]
#define OP  823296    // pwT   [16][1280]   (rows 12..15 zero)
#define NWS 843776    // weight elems
#define OGM 843776    // Gm fp32 [12][12] (288 bf16 elems)
#define OF2 844064    // F2 fp32 [12]     (24 elems)

// LDS byte offsets (54176 total -> 54272 alloc -> 3 blocks/CU, 12 waves/CU)
#define LA  0         // A: h0 raw -> h_b0 raw (T1)   [74][R64P] 10656
#define LB  10656     // Bf: gelu chain               [76][R64P] 10944 -> ends 21600
#define LC  10656     // C (TB1) overlays Bf post-L3  [68][320]sw 43520 -> ends 54176
#define LSZ 54176
// pass-2 aliases (dead regions only):
#define LRR 0         // enc-out [64][320]sw bf16 = 40960 (A,Bf,C dead)
#define LZB 40960     // per-wave z chunk [16][R64P] bf16 = 2304 x 4 waves -> 50176
#define LXI 50176     // x_interp fp32 [64][12] 3072 -> 53248
#define LGM 53248     // fc_w@fcr_w    [12][12] 576  -> 53824
#define LF2 53824     // fused bias    [12]     48   -> 53872

__device__ __forceinline__ float bf2f(const __hip_bfloat16 v) { return __bfloat162float(v); }
__device__ __forceinline__ __hip_bfloat16 f2bf(float f)       { return __float2bfloat16(f); }
__device__ __forceinline__ float geluf(float x) {
    return 0.5f * x * (1.0f + erff(x * 0.7071067811865475f));
}
__device__ __forceinline__ bf16x8 ldb8(const void* p) { return *(const bf16x8*)p; }
// XOR-swizzled [row][320] bf16 tile: byte = (row*640 + col*2) ^ ((row&7)<<4).
// Bijective within each row (640 = 5*128); b128 reads stay 16B-aligned; rows
// r..r+7 spread over 8 distinct 16B slots -> 2-way conflicts only (free).
__device__ __forceinline__ void* swp(void* base, int row, int col) {
    return (void*)((unsigned char*)base + (((row * 640 + col * 2)) ^ ((row & 7) << 4)));
}

// ---- weight prep: fp32 -> bf16 transposed + Gm/F2, every launch ------------
extern "C" __global__ void __launch_bounds__(256) prep_w(
    const float* __restrict__ c01w, const float* __restrict__ c02w,
    const float* __restrict__ c11w, const float* __restrict__ c12w,
    const float* __restrict__ c1pw, const float* __restrict__ dw,
    const float* __restrict__ pw,
    const float* __restrict__ fcw,  const float* __restrict__ fcb,
    const float* __restrict__ fcrw, const float* __restrict__ fcrb,
    __hip_bfloat16* __restrict__ ws)
{
    for (size_t i = (size_t)blockIdx.x * 256 + threadIdx.x; i < NWS;
         i += (size_t)gridDim.x * 256) {
        float v;
        if (i < O02)      { int q = (int)i;        int n = q / 192, r = q % 192;
                            v = c01w[(n * 64 + (r & 63)) * 3 + (r >> 6)]; }
        else if (i < O11) { int q = (int)(i - O02); int n = q / 192, r = q % 192;
                            v = c02w[(n * 64 + (r & 63)) * 3 + (r >> 6)]; }
        else if (i < O12) { int q = (int)(i - O11); int n = q / 192, r = q % 192;
                            v = c11w[(n * 64 + (r & 63)) * 3 + (r >> 6)]; }
        else if (i < OD)  { int q = (int)(i - O12); int n = q >> 10, k = q & 1023;
                            v = (k < 960) ? c12w[(n * 320 + (k % 320)) * 3 + (k / 320)]
                                          : c1pw[n * 64 + (k - 960)]; }
        else if (i < OP)  { int q = (int)(i - OD);  int h = q / 320, c = q % 320;
                            v = dw[c * 1280 + h]; }
        else              { int q = (int)(i - OP);  int j = q / 1280, h = q % 1280;
                            v = (j < 12) ? pw[h * 12 + j] : 0.f; }
        ws[i] = f2bf(v);
    }
    if (blockIdx.x == 0) {
        float* gm = (float*)(ws + OGM);
        float* f2 = (float*)(ws + OF2);
        for (int o = threadIdx.x; o < 144; o += 256) {
            int j = o / 12, j2 = o - j * 12;
            float s = 0.f;
            for (int c = 0; c < C1; c++) s += fcw[j * C1 + c] * fcrw[c * 12 + j2];
            gm[o] = s;
        }
        if (threadIdx.x < 12) {
            float s = fcrb[threadIdx.x];
            for (int c = 0; c < C1; c++) s += fcb[c] * fcrw[c * 12 + threadIdx.x];
            f2[threadIdx.x] = s;
        }
    }
}

extern "C" __global__ void __launch_bounds__(256, 3) fused_main(
    const float* __restrict__ x1,  const float* __restrict__ X1,
    const float* __restrict__ X2,
    const float* __restrict__ w_in, const float* __restrict__ b_in,
    const float* __restrict__ c01b, const float* __restrict__ c02b,
    const float* __restrict__ c1pb, const float* __restrict__ c11b,
    const float* __restrict__ c12b,
    const float* __restrict__ db,   const float* __restrict__ pb,
    const __hip_bfloat16* __restrict__ ws,
    float* __restrict__ out)
{
    __shared__ __align__(16) unsigned char smem[LSZ];
    __hip_bfloat16* A  = (__hip_bfloat16*)(smem + LA);   // h0 -> T1, 74 rows
    __hip_bfloat16* Bf = (__hip_bfloat16*)(smem + LB);   // G0 -> T0 -> GH, 76 rows
    unsigned char*  Cb = smem + LC;                      // TB1 [68][320]sw
    unsigned char*  Rb = smem + LRR;                     // enc-out [64][320]sw
    float* XI = (float*)(smem + LXI);
    float* Gm = (float*)(smem + LGM);
    float* F2 = (float*)(smem + LF2);

    const int tid  = threadIdx.x;
    const int wv   = tid >> 6;
    const int lane = tid & 63;
    const int lm   = lane & 15;        // MFMA: A row / B col / D col
    const int lq   = lane >> 4;        // MFMA: k-octet / D row-quad
    const int bid  = blockIdx.x;
    const int pass = bid % 3;          // interleave heavy pass-2 blocks
    const int rem  = bid / 3;
    const int b    = rem >> 3;
    const int t0   = (rem & (NTILE - 1)) * TT;
    const float* xin = (pass == 0) ? X1 : (pass == 1) ? X2 : x1;

    const f32x4 Z4 = {0.f, 0.f, 0.f, 0.f};

    // ---- L0: x@w_in + b_in, rows [0,76) ------------------------------------
    for (int o = tid; o < PP * C0; o += 256) {
        int p = o >> 6, c = o & 63;
        int t = t0 + p - HALO;
        float acc = 0.f;
        if (t >= 0 && t < TSEQ) {
            acc = b_in[c];
            const float4* xr4 = (const float4*)(xin + ((size_t)b * TSEQ + t) * DIN);
            float4 v0 = xr4[0], v1 = xr4[1], v2 = xr4[2];
            const float xv[12] = {v0.x, v0.y, v0.z, v0.w, v1.x, v1.y,
                                  v1.z, v1.w, v2.x, v2.y, v2.z, v2.w};
            #pragma unroll
            for (int i = 0; i < DIN; i++) acc += xv[i] * w_in[i * C0 + c];
        }
        if (p < 74) A[p * R64P + c] = f2bf(acc);   // A rows 74/75 never read
        Bf[p * R64P + c] = f2bf(geluf(acc));
    }
    __syncthreads();

    // ---- L1: conv0_1 64->64 k3 d1 on gelu(h0)=Bf, out rows [1,75) ----------
    {
        const int oc = wv * 16 + lm;
        bf16x8 bw[6];
        #pragma unroll
        for (int ks = 0; ks < 6; ks++)
            bw[ks] = ldb8(ws + O01 + oc * 192 + ks * 32 + (lq << 3));
        f32x4 acc[5] = {Z4, Z4, Z4, Z4, Z4};
        #pragma unroll
        for (int ks = 0; ks < 6; ks++) {
            int tap = ks >> 1, ci = ((ks & 1) << 5) + (lq << 3);
            #pragma unroll
            for (int mt = 0; mt < 5; mt++) {
                int p = 1 + mt * 16 + lm + tap - 1; p = p > 75 ? 75 : p;
                acc[mt] = MFMA16(ldb8(Bf + p * R64P + ci), bw[ks], acc[mt]);
            }
        }
        __syncthreads();   // all waves done reading G0 before in-place write
        float bias = c01b[oc];
        #pragma unroll
        for (int mt = 0; mt < 5; mt++)
            #pragma unroll
            for (int r = 0; r < 4; r++) {
                int m = mt * 16 + lq * 4 + r;
                if (m < 74) {
                    int p = 1 + m, t = t0 + p - HALO;
                    Bf[p * R64P + oc] =
                        f2bf((t >= 0 && t < TSEQ) ? geluf(acc[mt][r] + bias) : 0.f);
                }
            }
    }
    __syncthreads();

    // ---- L2: conv0_2 on T0=Bf + residual h0=A, out rows [2,74) -------------
    {
        const int oc = wv * 16 + lm;
        bf16x8 bw[6];
        #pragma unroll
        for (int ks = 0; ks < 6; ks++)
            bw[ks] = ldb8(ws + O02 + oc * 192 + ks * 32 + (lq << 3));
        f32x4 acc[5] = {Z4, Z4, Z4, Z4, Z4};
        #pragma unroll
        for (int ks = 0; ks < 6; ks++) {
            int tap = ks >> 1, ci = ((ks & 1) << 5) + (lq << 3);
            #pragma unroll
            for (int mt = 0; mt < 5; mt++) {
                int p = 2 + mt * 16 + lm + tap - 1; p = p > 75 ? 75 : p;
                acc[mt] = MFMA16(ldb8(Bf + p * R64P + ci), bw[ks], acc[mt]);
            }
        }
        float resv[5][4];
        #pragma unroll
        for (int mt = 0; mt < 5; mt++)
            #pragma unroll
            for (int r = 0; r < 4; r++) {
                int m = mt * 16 + lq * 4 + r;
                resv[mt][r] = (m < 72) ? bf2f(A[(2 + m) * R64P + oc]) : 0.f;
            }
        __syncthreads();   // reads of Bf and A complete
        float bias = c02b[oc];
        #pragma unroll
        for (int mt = 0; mt < 5; mt++)
            #pragma unroll
            for (int r = 0; r < 4; r++) {
                int m = mt * 16 + lq * 4 + r;
                if (m < 72) {
                    int p = 2 + m, t = t0 + p - HALO;
                    bool v = (t >= 0 && t < TSEQ);
                    float hb = acc[mt][r] + bias + resv[mt][r];
                    A [p * R64P + oc] = f2bf(v ? hb : 0.f);          // T1 raw
                    Bf[p * R64P + oc] = f2bf(v ? geluf(hb) : 0.f);   // GH
                }
            }
    }
    __syncthreads();

    // ---- L3: c1_1 64->320 k3 d2 on GH=Bf, out rows [4,72) -> C[m<68] -------
    // Un-pipelined (reg diet: accum 100 + a[5] 20 + 1 bw). 3 waves/SIMD TLP
    // covers the per-ks load latency.
    {
        f32x4 acc[5][5];
        #pragma unroll
        for (int mt = 0; mt < 5; mt++)
            #pragma unroll
            for (int nt = 0; nt < 5; nt++) acc[mt][nt] = Z4;
        #pragma unroll
        for (int ks = 0; ks < 6; ks++) {
            int tap = ks >> 1, ci = ((ks & 1) << 5) + (lq << 3);
            bf16x8 a[5];
            #pragma unroll
            for (int mt = 0; mt < 5; mt++) {
                int p = 4 + mt * 16 + lm + 2 * (tap - 1); p = p > 75 ? 75 : p;
                a[mt] = ldb8(Bf + p * R64P + ci);
            }
            #pragma unroll
            for (int nt = 0; nt < 5; nt++) {
                bf16x8 bw = ldb8(ws + O11 + (wv * 80 + nt * 16 + lm) * 192
                                 + ks * 32 + (lq << 3));
                #pragma unroll
                for (int mt = 0; mt < 5; mt++)
                    acc[mt][nt] = MFMA16(a[mt], bw, acc[mt][nt]);
            }
        }
        __syncthreads();   // all waves done reading Bf before C overlays it
        #pragma unroll
        for (int nt = 0; nt < 5; nt++) {
            int oc = wv * 80 + nt * 16 + lm;
            float bias = c11b[oc];
            #pragma unroll
            for (int mt = 0; mt < 5; mt++)
                #pragma unroll
                for (int r = 0; r < 4; r++) {
                    int m = mt * 16 + lq * 4 + r;
                    if (m < 68) {
                        int t = t0 + 4 + m - HALO;
                        *(__hip_bfloat16*)swp(Cb, m, oc) =
                            f2bf((t >= 0 && t < TSEQ) ? geluf(acc[mt][nt][r] + bias) : 0.f);
                    }
                }
        }
    }
    __syncthreads();

    // ---- L4: c1_2 320->320 k3 d2 (K=960) + c1_p 1x1 on T1=A (K=64) ---------
    // out rows [6,70) == 64 exactly. B-only ping-pong; A-frags in-body (LDS).
    {
        f32x4 acc[4][5];
        #pragma unroll
        for (int kk = 0; kk < 4; kk++)
            #pragma unroll
            for (int nt = 0; nt < 5; nt++) acc[kk][nt] = Z4;
        bf16x8 ba[5], bb[5];
        #pragma unroll
        for (int nt = 0; nt < 5; nt++)
            ba[nt] = ldb8(ws + O12 + (wv * 80 + nt * 16 + lm) * 1024 + (lq << 3));
        for (int ks = 0; ks < 32; ks += 2) {
            // prefetch B for ks+1
            #pragma unroll
            for (int nt = 0; nt < 5; nt++)
                bb[nt] = ldb8(ws + O12 + (wv * 80 + nt * 16 + lm) * 1024
                              + (ks + 1) * 32 + (lq << 3));
            {   // body even: ks
                bf16x8 a[4];
                if (ks < 30) {
                    int tap = (ks >= 20) ? 2 : (ks >= 10 ? 1 : 0);
                    int ci = (ks - tap * 10) * 32 + (lq << 3);
                    #pragma unroll
                    for (int mt = 0; mt < 4; mt++)
                        a[mt] = ldb8(swp(Cb, 2 + mt * 16 + lm + 2 * (tap - 1), ci));
                } else {
                    int ci = ((ks - 30) << 5) + (lq << 3);
                    #pragma unroll
                    for (int mt = 0; mt < 4; mt++)
                        a[mt] = ldb8(A + (6 + mt * 16 + lm) * R64P + ci);
                }
                #pragma unroll
                for (int nt = 0; nt < 5; nt++)
                    #pragma unroll
                    for (int mt = 0; mt < 4; mt++)
                        acc[mt][nt] = MFMA16(a[mt], ba[nt], acc[mt][nt]);
            }
            // prefetch B for ks+2
            if (ks + 2 < 32)
                #pragma unroll
                for (int nt = 0; nt < 5; nt++)
                    ba[nt] = ldb8(ws + O12 + (wv * 80 + nt * 16 + lm) * 1024
                                  + (ks + 2) * 32 + (lq << 3));
            {   // body odd: ks+1
                int k1 = ks + 1;
                bf16x8 a[4];
                if (k1 < 30) {
                    int tap = (k1 >= 20) ? 2 : (k1 >= 10 ? 1 : 0);
                    int ci = (k1 - tap * 10) * 32 + (lq << 3);
                    #pragma unroll
                    for (int mt = 0; mt < 4; mt++)
                        a[mt] = ldb8(swp(Cb, 2 + mt * 16 + lm + 2 * (tap - 1), ci));
                } else {
                    int ci = ((k1 - 30) << 5) + (lq << 3);
                    #pragma unroll
                    for (int mt = 0; mt < 4; mt++)
                        a[mt] = ldb8(A + (6 + mt * 16 + lm) * R64P + ci);
                }
                #pragma unroll
                for (int nt = 0; nt < 5; nt++)
                    #pragma unroll
                    for (int mt = 0; mt < 4; mt++)
                        acc[mt][nt] = MFMA16(a[mt], bb[nt], acc[mt][nt]);
            }
        }
        if (pass < 2) {
            #pragma unroll
            for (int nt = 0; nt < 5; nt++) {
                int oc = wv * 80 + nt * 16 + lm;
                float bias = c12b[oc] + c1pb[oc];
                const size_t obase = (pass == 1) ? S1 : (size_t)0;
                #pragma unroll
                for (int mt = 0; mt < 4; mt++)
                    #pragma unroll
                    for (int r = 0; r < 4; r++) {
                        int m = mt * 16 + lq * 4 + r;
                        out[obase + ((size_t)b * TSEQ + t0 + m) * C1 + oc] =
                            acc[mt][nt][r] + bias;
                    }
            }
        } else {
            __syncthreads();   // all waves done reading C,A -> safe to alias
            #pragma unroll
            for (int nt = 0; nt < 5; nt++) {
                int oc = wv * 80 + nt * 16 + lm;
                float bias = c12b[oc] + c1pb[oc];
                #pragma unroll
                for (int mt = 0; mt < 4; mt++)
                    #pragma unroll
                    for (int r = 0; r < 4; r++) {
                        int m = mt * 16 + lq * 4 + r;
                        *(__hip_bfloat16*)swp(Rb, m, oc) = f2bf(acc[mt][nt][r] + bias);
                    }
            }
            // init XI/Gm/F2 (their region overlapped C, which is dead now)
            const float* gmw = (const float*)(ws + OGM);
            const float* f2w = (const float*)(ws + OF2);
            for (int o = tid; o < TT * 12; o += 256) XI[o] = pb[o % 12];
            for (int o = tid; o < 144; o += 256) Gm[o] = gmw[o];
            if (tid < 12) F2[tid] = f2w[tid];
            __syncthreads();   // Rr + XI/Gm/F2 complete
        }
    }

    // ---- pass-2: dense 320->1280, relu, @pw (MFMA), @Gm, outputs -----------
    if (pass == 2) {
        __hip_bfloat16* zb = (__hip_bfloat16*)(smem + LZB) + wv * (16 * R64P);
        f32x4 xacc[4] = {Z4, Z4, Z4, Z4};
        for (int cn = 0; cn < 5; cn++) {
            const int h0 = wv * 320 + cn * 64;
            f32x4 dacc[4][4];
            #pragma unroll
            for (int mt = 0; mt < 4; mt++)
                #pragma unroll
                for (int nt = 0; nt < 4; nt++) dacc[mt][nt] = Z4;
            bf16x8 ba[4], bb[4];
            #pragma unroll
            for (int nt = 0; nt < 4; nt++)
                ba[nt] = ldb8(ws + OD + (h0 + nt * 16 + lm) * 320 + (lq << 3));
            for (int ks = 0; ks < 10; ks += 2) {
                #pragma unroll
                for (int nt = 0; nt < 4; nt++)
                    bb[nt] = ldb8(ws + OD + (h0 + nt * 16 + lm) * 320
                                  + (ks + 1) * 32 + (lq << 3));
                {
                    bf16x8 a[4];
                    #pragma unroll
                    for (int mt = 0; mt < 4; mt++)
                        a[mt] = ldb8(swp(Rb, mt * 16 + lm, ks * 32 + (lq << 3)));
                    #pragma unroll
                    for (int nt = 0; nt < 4; nt++)
                        #pragma unroll
                        for (int mt = 0; mt < 4; mt++)
                            dacc[mt][nt] = MFMA16(a[mt], ba[nt], dacc[mt][nt]);
                }
                if (ks + 2 < 10)
                    #pragma unroll
                    for (int nt = 0; nt < 4; nt++)
                        ba[nt] = ldb8(ws + OD + (h0 + nt * 16 + lm) * 320
                                      + (ks + 2) * 32 + (lq << 3));
                {
                    bf16x8 a[4];
                    #pragma unroll
                    for (int mt = 0; mt < 4; mt++)
                        a[mt] = ldb8(swp(Rb, mt * 16 + lm, (ks + 1) * 32 + (lq << 3)));
                    #pragma unroll
                    for (int nt = 0; nt < 4; nt++)
                        #pragma unroll
                        for (int mt = 0; mt < 4; mt++)
                            dacc[mt][nt] = MFMA16(a[mt], bb[nt], dacc[mt][nt]);
                }
            }
            // per-mt: relu -> zb (wave-private, DS in-order) -> proj MFMA
            #pragma unroll
            for (int mt = 0; mt < 4; mt++) {
                #pragma unroll
                for (int nt = 0; nt < 4; nt++) {
                    int h = h0 + nt * 16 + lm;
                    float dbv = db[h];
                    #pragma unroll
                    for (int r = 0; r < 4; r++)
                        zb[(lq * 4 + r) * R64P + nt * 16 + lm] =
                            f2bf(fmaxf(dacc[mt][nt][r] + dbv, 0.f));
                }
                #pragma unroll
                for (int k2 = 0; k2 < 2; k2++) {
                    int hl = k2 * 32 + (lq << 3);
                    bf16x8 bf = ldb8(ws + OP + lm * 1280 + h0 + hl);
                    xacc[mt] = MFMA16(ldb8(zb + lm * R64P + hl), bf, xacc[mt]);
                }
            }
        }
        if (lm < 12) {
            #pragma unroll
            for (int mt = 0; mt < 4; mt++)
                #pragma unroll
                for (int r = 0; r < 4; r++)
                    atomicAdd(&XI[(mt * 16 + lq * 4 + r) * 12 + lm], xacc[mt][r]);
        }
        __syncthreads();
        for (int o = tid; o < TT * 12; o += 256) {
            int p = o / 12, j2 = o - p * 12;
            float val = F2[j2];
            #pragma unroll
            for (int j = 0; j < 12; j++) val += XI[p * 12 + j] * Gm[j * 12 + j2];
            size_t idx = ((size_t)b * TSEQ + t0 + p) * DIN + j2;
            out[2 * S1 + idx]      = val;   // outputs1
            out[2 * S1 + S2 + idx] = val;   // outputs2 (ref uses y_t1 for both)
        }
    }
}

// ---- masks + passthrough: m1, m2, x1, x2 -----------------------------------
extern "C" __global__ void __launch_bounds__(256) tail_kernel(
    const float* __restrict__ x1, const float* __restrict__ x2,
    float* __restrict__ out)
{
    size_t i = (size_t)blockIdx.x * 256 + threadIdx.x;
    if (i >= S2) return;
    float a = x1[i], c = x2[i];
    const size_t base = 2 * S1 + 2 * S2;
    out[base + i]          = (a != 0.f) ? 1.f : 0.f;
    out[base + S2 + i]     = (c != 0.f) ? 1.f : 0.f;
    out[base + 2 * S2 + i] = a;
    out[base + 3 * S2 + i] = c;
}

extern "C" void kernel_launch(void* const* d_in, const int* in_sizes, int n_in,
                              void* d_out, int out_size, void* d_ws, size_t ws_size,
                              hipStream_t stream)
{
    (void)in_sizes; (void)n_in; (void)ws_size; (void)out_size;
    const float* x1   = (const float*)d_in[0];
    const float* x2   = (const float*)d_in[1];
    const float* X1   = (const float*)d_in[2];
    const float* X2   = (const float*)d_in[3];
    const float* w_in = (const float*)d_in[5];
    const float* b_in = (const float*)d_in[6];
    const float* c01w = (const float*)d_in[7];
    const float* c01b = (const float*)d_in[8];
    const float* c02w = (const float*)d_in[9];
    const float* c02b = (const float*)d_in[10];
    const float* c1pw = (const float*)d_in[11];
    const float* c1pb = (const float*)d_in[12];
    const float* c11w = (const float*)d_in[13];
    const float* c11b = (const float*)d_in[14];
    const float* c12w = (const float*)d_in[15];
    const float* c12b = (const float*)d_in[16];
    const float* dwp  = (const float*)d_in[17];
    const float* dbp  = (const float*)d_in[18];
    const float* pwp  = (const float*)d_in[19];
    const float* pbp  = (const float*)d_in[20];
    const float* fcw  = (const float*)d_in[21];
    const float* fcb  = (const float*)d_in[22];
    const float* fcrw = (const float*)d_in[29];
    const float* fcrb = (const float*)d_in[30];
    float* out = (float*)d_out;
    __hip_bfloat16* ws = (__hip_bfloat16*)d_ws;

    prep_w<<<824, 256, 0, stream>>>(c01w, c02w, c11w, c12w, c1pw, dwp, pwp,
                                    fcw, fcb, fcrw, fcrb, ws);

    fused_main<<<3 * BB * NTILE, 256, 0, stream>>>(
        x1, X1, X2, w_in, b_in, c01b, c02b, c1pb, c11b, c12b,
        dbp, pbp, ws, out);

    tail_kernel<<<(int)((S2 + 255) / 256), 256, 0, stream>>>(x1, x2, out);
}

// Round 6
// 838.083 us; speedup vs baseline: 1.5053x; 1.1143x over previous
//
#include <hip/hip_runtime.h>
#include <hip/hip_bf16.h>
#include <math.h>

// ---------------------------------------------------------------------------
// TSRL fused forward, MFMA edition (round 10: r6 base + depth-2 B prefetch).
// Round-9 post-mortem: (256,3) reg diet -> spills (FETCH 132MB/WRITE 402MB),
// occupancy flat 20.5%, 736us. Swizzle DID cut bank conflicts 3x. Evidence
// r5/r7/r8/r9: occupancy trades always lose; r6 (pipelining+TT=64) is champ.
// Stall math: ~350-400 cyc avg per phase = L2-hit-under-load on B-frags;
// r6's depth-1 ping-pong covers only ~96 cyc. This round:
//  * r6 structure exactly ((256,2) -> 256-reg budget, no diet, no spills).
//  * L4 B-prefetch depth-2: period-3 rotation b0/b1/b2 over the 30 conv
//    phases (5 outer x 6 statically-named phases), T1 phases 30/31 epilogue.
//    A stays depth-1 ping-pong (LDS ~120cy < 1-phase cover + slack).
//  * C/Rr stored [.][320] with XOR swizzle byte^=(row&7)<<4 (r9-verified:
//    conflict-free b128 reads, bijective per row since 640%128==0).
//  * A trimmed to 74 rows (r9-verified). XI/Gm/F2 static at 54176 (disjoint
//    from C which ends exactly there).
// Masking per round 6: L1 m<74, L2 m<72, L3 m<68, L4 exact 64.
// Tripwire: FETCH ~26MB / WRITE ~170MB. If ballooned => spills => revert.
// ---------------------------------------------------------------------------

#define BB    128
#define TSEQ  512
#define NTILE 8
#define DIN   12
#define C0    64
#define C1    320
#define TT    64
#define PP    76
#define HALO  6
#define R64P  72      // bf16 elems/row (144B = 36 dw == 4 mod 32)

#define S1 ((size_t)BB * TSEQ * C1)
#define S2 ((size_t)BB * TSEQ * DIN)

typedef __attribute__((ext_vector_type(8))) __bf16 bf16x8;
typedef __attribute__((ext_vector_type(4))) float f32x4;
#define MFMA16(a, b, c) __builtin_amdgcn_mfma_f32_16x16x32_bf16(a, b, c, 0, 0, 0)

// workspace (bf16 elem offsets): transposed bf16 weights Bt[n][k]
#define O01 0         // c01wT [64][192]
#define O02 12288     // c02wT [64][192]
#define O11 24576     // c11wT [320][192]
#define O12 86016     // c12wT [320][1024]  (k<960: conv taps; k>=960: c1_p 1x1)
#define OD  413696    // dwT   [1280][320]
#define OP  823296    // pwT   [16][1280]   (rows 12..15 zero)
#define NWS 843776    // weight elems
#define OGM 843776    // Gm fp32 [12][12] (288 bf16 elems)
#define OF2 844064    // F2 fp32 [12]     (24 elems)

// LDS byte offsets (57872 total => 2 blocks/CU)
#define LA  0         // A: h0 raw -> h_b0 raw (T1)   [74][R64P] 10656
#define LB  10656     // Bf: gelu chain               [76][R64P] 10944 -> 21600
#define LC  10656     // C (TB1) overlays Bf post-L3  [68][640B]sw -> ends 54176
#define LXI 54176     // x_interp fp32 [64][12] 3072 -> 57248 (disjoint from C)
#define LGM 57248     // fc_w@fcr_w    [12][12] 576  -> 57824
#define LF2 57824     // fused bias    [12]     48   -> 57872
#define LSZ 57872
// pass-2 aliases (dead regions only):
#define LRR 0         // enc-out [64][640B]sw = 40960 (A,Bf,C dead)
#define LZB 40960     // per-wave z chunk [16][R64P] bf16 = 2304 x 4 -> 50176

__device__ __forceinline__ float bf2f(const __hip_bfloat16 v) { return __bfloat162float(v); }
__device__ __forceinline__ __hip_bfloat16 f2bf(float f)       { return __float2bfloat16(f); }
__device__ __forceinline__ float geluf(float x) {
    return 0.5f * x * (1.0f + erff(x * 0.7071067811865475f));
}
__device__ __forceinline__ bf16x8 ldb8(const void* p) { return *(const bf16x8*)p; }
// XOR-swizzled [row][320] bf16 tile: byte = (row*640 + col*2) ^ ((row&7)<<4).
// 640 % 128 == 0 -> each row 128-aligned; XOR of bits 4..6 stays in-row,
// bijective, keeps 16B alignment; rows r..r+7 spread across 8 16B slots.
__device__ __forceinline__ void* swp(void* base, int row, int col) {
    return (void*)((unsigned char*)base + ((row * 640 + col * 2) ^ ((row & 7) << 4)));
}

// ---- weight prep: fp32 -> bf16 transposed + Gm/F2, every launch ------------
extern "C" __global__ void __launch_bounds__(256) prep_w(
    const float* __restrict__ c01w, const float* __restrict__ c02w,
    const float* __restrict__ c11w, const float* __restrict__ c12w,
    const float* __restrict__ c1pw, const float* __restrict__ dw,
    const float* __restrict__ pw,
    const float* __restrict__ fcw,  const float* __restrict__ fcb,
    const float* __restrict__ fcrw, const float* __restrict__ fcrb,
    __hip_bfloat16* __restrict__ ws)
{
    for (size_t i = (size_t)blockIdx.x * 256 + threadIdx.x; i < NWS;
         i += (size_t)gridDim.x * 256) {
        float v;
        if (i < O02)      { int q = (int)i;        int n = q / 192, r = q % 192;
                            v = c01w[(n * 64 + (r & 63)) * 3 + (r >> 6)]; }
        else if (i < O11) { int q = (int)(i - O02); int n = q / 192, r = q % 192;
                            v = c02w[(n * 64 + (r & 63)) * 3 + (r >> 6)]; }
        else if (i < O12) { int q = (int)(i - O11); int n = q / 192, r = q % 192;
                            v = c11w[(n * 64 + (r & 63)) * 3 + (r >> 6)]; }
        else if (i < OD)  { int q = (int)(i - O12); int n = q >> 10, k = q & 1023;
                            v = (k < 960) ? c12w[(n * 320 + (k % 320)) * 3 + (k / 320)]
                                          : c1pw[n * 64 + (k - 960)]; }
        else if (i < OP)  { int q = (int)(i - OD);  int h = q / 320, c = q % 320;
                            v = dw[c * 1280 + h]; }
        else              { int q = (int)(i - OP);  int j = q / 1280, h = q % 1280;
                            v = (j < 12) ? pw[h * 12 + j] : 0.f; }
        ws[i] = f2bf(v);
    }
    if (blockIdx.x == 0) {
        float* gm = (float*)(ws + OGM);
        float* f2 = (float*)(ws + OF2);
        for (int o = threadIdx.x; o < 144; o += 256) {
            int j = o / 12, j2 = o - j * 12;
            float s = 0.f;
            for (int c = 0; c < C1; c++) s += fcw[j * C1 + c] * fcrw[c * 12 + j2];
            gm[o] = s;
        }
        if (threadIdx.x < 12) {
            float s = fcrb[threadIdx.x];
            for (int c = 0; c < C1; c++) s += fcb[c] * fcrw[c * 12 + threadIdx.x];
            f2[threadIdx.x] = s;
        }
    }
}

extern "C" __global__ void __launch_bounds__(256, 2) fused_main(
    const float* __restrict__ x1,  const float* __restrict__ X1,
    const float* __restrict__ X2,
    const float* __restrict__ w_in, const float* __restrict__ b_in,
    const float* __restrict__ c01b, const float* __restrict__ c02b,
    const float* __restrict__ c1pb, const float* __restrict__ c11b,
    const float* __restrict__ c12b,
    const float* __restrict__ db,   const float* __restrict__ pb,
    const __hip_bfloat16* __restrict__ ws,
    float* __restrict__ out)
{
    __shared__ __align__(16) unsigned char smem[LSZ];
    __hip_bfloat16* A  = (__hip_bfloat16*)(smem + LA);   // h0 -> T1, 74 rows
    __hip_bfloat16* Bf = (__hip_bfloat16*)(smem + LB);   // G0 -> T0 -> GH, 76 rows
    unsigned char*  Cb = smem + LC;                      // TB1 [68][320]sw
    unsigned char*  Rb = smem + LRR;                     // enc-out [64][320]sw
    float* XI = (float*)(smem + LXI);
    float* Gm = (float*)(smem + LGM);
    float* F2 = (float*)(smem + LF2);

    const int tid  = threadIdx.x;
    const int wv   = tid >> 6;
    const int lane = tid & 63;
    const int lm   = lane & 15;        // MFMA: A row / B col / D col
    const int lq   = lane >> 4;        // MFMA: k-octet / D row-quad
    const int bid  = blockIdx.x;
    const int pass = bid % 3;          // interleave heavy pass-2 blocks
    const int rem  = bid / 3;
    const int b    = rem >> 3;
    const int t0   = (rem & (NTILE - 1)) * TT;
    const float* xin = (pass == 0) ? X1 : (pass == 1) ? X2 : x1;

    const f32x4 Z4 = {0.f, 0.f, 0.f, 0.f};

    // ---- pass-2 prep: load Gm/F2 from ws, XI = ih_proj_b (region disjoint) -
    if (pass == 2) {
        const float* gmw = (const float*)(ws + OGM);
        const float* f2w = (const float*)(ws + OF2);
        for (int o = tid; o < 144; o += 256) Gm[o] = gmw[o];
        if (tid < 12) F2[tid] = f2w[tid];
        for (int o = tid; o < TT * 12; o += 256) XI[o] = pb[o % 12];
    }

    // ---- L0: x@w_in + b_in, rows [0,76) ------------------------------------
    for (int o = tid; o < PP * C0; o += 256) {
        int p = o >> 6, c = o & 63;
        int t = t0 + p - HALO;
        float acc = 0.f;
        if (t >= 0 && t < TSEQ) {
            acc = b_in[c];
            const float4* xr4 = (const float4*)(xin + ((size_t)b * TSEQ + t) * DIN);
            float4 v0 = xr4[0], v1 = xr4[1], v2 = xr4[2];
            const float xv[12] = {v0.x, v0.y, v0.z, v0.w, v1.x, v1.y,
                                  v1.z, v1.w, v2.x, v2.y, v2.z, v2.w};
            #pragma unroll
            for (int i = 0; i < DIN; i++) acc += xv[i] * w_in[i * C0 + c];
        }
        if (p < 74) A[p * R64P + c] = f2bf(acc);   // A rows 74/75 never read
        Bf[p * R64P + c] = f2bf(geluf(acc));
    }
    __syncthreads();

    // ---- L1: conv0_1 64->64 k3 d1 on gelu(h0)=Bf, out rows [1,75) ----------
    {
        const int oc = wv * 16 + lm;
        bf16x8 bw[6];
        #pragma unroll
        for (int ks = 0; ks < 6; ks++)
            bw[ks] = ldb8(ws + O01 + oc * 192 + ks * 32 + (lq << 3));
        f32x4 acc[5] = {Z4, Z4, Z4, Z4, Z4};
        #pragma unroll
        for (int ks = 0; ks < 6; ks++) {
            int tap = ks >> 1, ci = ((ks & 1) << 5) + (lq << 3);
            #pragma unroll
            for (int mt = 0; mt < 5; mt++) {
                int p = 1 + mt * 16 + lm + tap - 1; p = p > 75 ? 75 : p;
                acc[mt] = MFMA16(ldb8(Bf + p * R64P + ci), bw[ks], acc[mt]);
            }
        }
        __syncthreads();   // all waves done reading G0 before in-place write
        float bias = c01b[oc];
        #pragma unroll
        for (int mt = 0; mt < 5; mt++)
            #pragma unroll
            for (int r = 0; r < 4; r++) {
                int m = mt * 16 + lq * 4 + r;
                if (m < 74) {
                    int p = 1 + m, t = t0 + p - HALO;
                    Bf[p * R64P + oc] =
                        f2bf((t >= 0 && t < TSEQ) ? geluf(acc[mt][r] + bias) : 0.f);
                }
            }
    }
    __syncthreads();

    // ---- L2: conv0_2 on T0=Bf + residual h0=A, out rows [2,74) -------------
    {
        const int oc = wv * 16 + lm;
        bf16x8 bw[6];
        #pragma unroll
        for (int ks = 0; ks < 6; ks++)
            bw[ks] = ldb8(ws + O02 + oc * 192 + ks * 32 + (lq << 3));
        f32x4 acc[5] = {Z4, Z4, Z4, Z4, Z4};
        #pragma unroll
        for (int ks = 0; ks < 6; ks++) {
            int tap = ks >> 1, ci = ((ks & 1) << 5) + (lq << 3);
            #pragma unroll
            for (int mt = 0; mt < 5; mt++) {
                int p = 2 + mt * 16 + lm + tap - 1; p = p > 75 ? 75 : p;
                acc[mt] = MFMA16(ldb8(Bf + p * R64P + ci), bw[ks], acc[mt]);
            }
        }
        float resv[5][4];
        #pragma unroll
        for (int mt = 0; mt < 5; mt++)
            #pragma unroll
            for (int r = 0; r < 4; r++) {
                int m = mt * 16 + lq * 4 + r;
                resv[mt][r] = (m < 72) ? bf2f(A[(2 + m) * R64P + oc]) : 0.f;
            }
        __syncthreads();   // reads of Bf and A complete
        float bias = c02b[oc];
        #pragma unroll
        for (int mt = 0; mt < 5; mt++)
            #pragma unroll
            for (int r = 0; r < 4; r++) {
                int m = mt * 16 + lq * 4 + r;
                if (m < 72) {
                    int p = 2 + m, t = t0 + p - HALO;
                    bool v = (t >= 0 && t < TSEQ);
                    float hb = acc[mt][r] + bias + resv[mt][r];
                    A [p * R64P + oc] = f2bf(v ? hb : 0.f);          // T1 raw
                    Bf[p * R64P + oc] = f2bf(v ? geluf(hb) : 0.f);   // GH
                }
            }
    }
    __syncthreads();

    // ---- L3: c1_1 64->320 k3 d2 on GH=Bf, out rows [4,72) -> C[m<68] -------
    // B ping-pong depth-1 (r6-proven); A in-phase.
    {
        f32x4 acc[5][5];
        #pragma unroll
        for (int mt = 0; mt < 5; mt++)
            #pragma unroll
            for (int nt = 0; nt < 5; nt++) acc[mt][nt] = Z4;
        bf16x8 bcur[5], bnxt[5];
        #pragma unroll
        for (int nt = 0; nt < 5; nt++)
            bcur[nt] = ldb8(ws + O11 + (wv * 80 + nt * 16 + lm) * 192 + (lq << 3));
        #pragma unroll
        for (int ks = 0; ks < 6; ks++) {
            if (ks < 5)
                #pragma unroll
                for (int nt = 0; nt < 5; nt++)
                    bnxt[nt] = ldb8(ws + O11 + (wv * 80 + nt * 16 + lm) * 192
                                    + (ks + 1) * 32 + (lq << 3));
            int tap = ks >> 1, ci = ((ks & 1) << 5) + (lq << 3);
            bf16x8 a[5];
            #pragma unroll
            for (int mt = 0; mt < 5; mt++) {
                int p = 4 + mt * 16 + lm + 2 * (tap - 1); p = p > 75 ? 75 : p;
                a[mt] = ldb8(Bf + p * R64P + ci);
            }
            #pragma unroll
            for (int nt = 0; nt < 5; nt++)
                #pragma unroll
                for (int mt = 0; mt < 5; mt++)
                    acc[mt][nt] = MFMA16(a[mt], bcur[nt], acc[mt][nt]);
            #pragma unroll
            for (int nt = 0; nt < 5; nt++) bcur[nt] = bnxt[nt];
        }
        __syncthreads();   // all waves done reading Bf before C overlays it
        #pragma unroll
        for (int nt = 0; nt < 5; nt++) {
            int oc = wv * 80 + nt * 16 + lm;
            float bias = c11b[oc];
            #pragma unroll
            for (int mt = 0; mt < 5; mt++)
                #pragma unroll
                for (int r = 0; r < 4; r++) {
                    int m = mt * 16 + lq * 4 + r;
                    if (m < 68) {
                        int t = t0 + 4 + m - HALO;
                        *(__hip_bfloat16*)swp(Cb, m, oc) =
                            f2bf((t >= 0 && t < TSEQ) ? geluf(acc[mt][nt][r] + bias) : 0.f);
                    }
                }
        }
    }
    __syncthreads();

    // ---- L4: c1_2 320->320 k3 d2 (K=960) + c1_p 1x1 on T1=A (K=64) ---------
    // out rows [6,70) == 64 exactly. B depth-2 (period-3 rotation, 5x6
    // statically-named phases for ks 0..29), A depth-1 ping-pong.
    {
        f32x4 acc[4][5];
        #pragma unroll
        for (int mt = 0; mt < 4; mt++)
            #pragma unroll
            for (int nt = 0; nt < 5; nt++) acc[mt][nt] = Z4;
        bf16x8 a0[4], a1[4], b0[5], b1[5], b2[5];
        auto LDA = [&](int ks, bf16x8 (&a)[4]) {
            if (ks < 30) {
                int tap = (ks >= 20) ? 2 : (ks >= 10 ? 1 : 0);
                int ci = (ks - tap * 10) * 32 + (lq << 3);
                #pragma unroll
                for (int mt = 0; mt < 4; mt++)
                    a[mt] = ldb8(swp(Cb, 2 + mt * 16 + lm + 2 * (tap - 1), ci));
            } else {
                int ci = ((ks - 30) << 5) + (lq << 3);
                #pragma unroll
                for (int mt = 0; mt < 4; mt++)
                    a[mt] = ldb8(A + (6 + mt * 16 + lm) * R64P + ci);
            }
        };
        auto LDB = [&](int ks, bf16x8 (&bw)[5]) {
            #pragma unroll
            for (int nt = 0; nt < 5; nt++)
                bw[nt] = ldb8(ws + O12 + (wv * 80 + nt * 16 + lm) * 1024
                              + ks * 32 + (lq << 3));
        };
        auto FMA = [&](bf16x8 (&a)[4], bf16x8 (&bw)[5]) {
            #pragma unroll
            for (int nt = 0; nt < 5; nt++)
                #pragma unroll
                for (int mt = 0; mt < 4; mt++)
                    acc[mt][nt] = MFMA16(a[mt], bw[nt], acc[mt][nt]);
        };
        LDA(0, a0); LDB(0, b0); LDB(1, b1);
        for (int g = 0; g < 5; g++) {
            int p = 6 * g;
            LDA(p + 1, a1); LDB(p + 2, b2); FMA(a0, b0);
            LDA(p + 2, a0); LDB(p + 3, b0); FMA(a1, b1);
            LDA(p + 3, a1); LDB(p + 4, b1); FMA(a0, b2);
            LDA(p + 4, a0); LDB(p + 5, b2); FMA(a1, b0);
            LDA(p + 5, a1); LDB(p + 6, b0); FMA(a0, b1);
            LDA(p + 6, a0); LDB(p + 7, b1); FMA(a1, b2);
        }
        // phases 30,31 (T1): a0=A(30), b0=B(30), b1=B(31) already loaded
        LDA(31, a1); FMA(a0, b0);
        FMA(a1, b1);

        if (pass < 2) {
            #pragma unroll
            for (int nt = 0; nt < 5; nt++) {
                int oc = wv * 80 + nt * 16 + lm;
                float bias = c12b[oc] + c1pb[oc];
                const size_t obase = (pass == 1) ? S1 : (size_t)0;
                #pragma unroll
                for (int mt = 0; mt < 4; mt++)
                    #pragma unroll
                    for (int r = 0; r < 4; r++) {
                        int m = mt * 16 + lq * 4 + r;
                        out[obase + ((size_t)b * TSEQ + t0 + m) * C1 + oc] =
                            acc[mt][nt][r] + bias;
                    }
            }
        } else {
            __syncthreads();   // all waves done reading C,A -> safe to alias
            #pragma unroll
            for (int nt = 0; nt < 5; nt++) {
                int oc = wv * 80 + nt * 16 + lm;
                float bias = c12b[oc] + c1pb[oc];
                #pragma unroll
                for (int mt = 0; mt < 4; mt++)
                    #pragma unroll
                    for (int r = 0; r < 4; r++) {
                        int m = mt * 16 + lq * 4 + r;
                        *(__hip_bfloat16*)swp(Rb, m, oc) = f2bf(acc[mt][nt][r] + bias);
                    }
            }
            __syncthreads();   // Rr complete (cross-wave K in dense stage)
        }
    }

    // ---- pass-2: dense 320->1280, relu, @pw (MFMA), @Gm, outputs -----------
    if (pass == 2) {
        __hip_bfloat16* zb = (__hip_bfloat16*)(smem + LZB) + wv * (16 * R64P);
        f32x4 xacc[4] = {Z4, Z4, Z4, Z4};
        for (int cn = 0; cn < 5; cn++) {
            const int h0 = wv * 320 + cn * 64;
            f32x4 dacc[4][4];
            #pragma unroll
            for (int mt = 0; mt < 4; mt++)
                #pragma unroll
                for (int nt = 0; nt < 4; nt++) dacc[mt][nt] = Z4;
            bf16x8 ba[4], bb[4];
            #pragma unroll
            for (int nt = 0; nt < 4; nt++)
                ba[nt] = ldb8(ws + OD + (h0 + nt * 16 + lm) * 320 + (lq << 3));
            for (int ks = 0; ks < 10; ks += 2) {
                #pragma unroll
                for (int nt = 0; nt < 4; nt++)
                    bb[nt] = ldb8(ws + OD + (h0 + nt * 16 + lm) * 320
                                  + (ks + 1) * 32 + (lq << 3));
                {
                    bf16x8 a[4];
                    #pragma unroll
                    for (int mt = 0; mt < 4; mt++)
                        a[mt] = ldb8(swp(Rb, mt * 16 + lm, ks * 32 + (lq << 3)));
                    #pragma unroll
                    for (int nt = 0; nt < 4; nt++)
                        #pragma unroll
                        for (int mt = 0; mt < 4; mt++)
                            dacc[mt][nt] = MFMA16(a[mt], ba[nt], dacc[mt][nt]);
                }
                if (ks + 2 < 10)
                    #pragma unroll
                    for (int nt = 0; nt < 4; nt++)
                        ba[nt] = ldb8(ws + OD + (h0 + nt * 16 + lm) * 320
                                      + (ks + 2) * 32 + (lq << 3));
                {
                    bf16x8 a[4];
                    #pragma unroll
                    for (int mt = 0; mt < 4; mt++)
                        a[mt] = ldb8(swp(Rb, mt * 16 + lm, (ks + 1) * 32 + (lq << 3)));
                    #pragma unroll
                    for (int nt = 0; nt < 4; nt++)
                        #pragma unroll
                        for (int mt = 0; mt < 4; mt++)
                            dacc[mt][nt] = MFMA16(a[mt], bb[nt], dacc[mt][nt]);
                }
            }
            // per-mt: relu -> zb (wave-private, DS in-order) -> proj MFMA
            #pragma unroll
            for (int mt = 0; mt < 4; mt++) {
                #pragma unroll
                for (int nt = 0; nt < 4; nt++) {
                    int h = h0 + nt * 16 + lm;
                    float dbv = db[h];
                    #pragma unroll
                    for (int r = 0; r < 4; r++)
                        zb[(lq * 4 + r) * R64P + nt * 16 + lm] =
                            f2bf(fmaxf(dacc[mt][nt][r] + dbv, 0.f));
                }
                #pragma unroll
                for (int k2 = 0; k2 < 2; k2++) {
                    int hl = k2 * 32 + (lq << 3);
                    bf16x8 bf = ldb8(ws + OP + lm * 1280 + h0 + hl);
                    xacc[mt] = MFMA16(ldb8(zb + lm * R64P + hl), bf, xacc[mt]);
                }
            }
        }
        if (lm < 12) {
            #pragma unroll
            for (int mt = 0; mt < 4; mt++)
                #pragma unroll
                for (int r = 0; r < 4; r++)
                    atomicAdd(&XI[(mt * 16 + lq * 4 + r) * 12 + lm], xacc[mt][r]);
        }
        __syncthreads();
        for (int o = tid; o < TT * 12; o += 256) {
            int p = o / 12, j2 = o - p * 12;
            float val = F2[j2];
            #pragma unroll
            for (int j = 0; j < 12; j++) val += XI[p * 12 + j] * Gm[j * 12 + j2];
            size_t idx = ((size_t)b * TSEQ + t0 + p) * DIN + j2;
            out[2 * S1 + idx]      = val;   // outputs1
            out[2 * S1 + S2 + idx] = val;   // outputs2 (ref uses y_t1 for both)
        }
    }
}

// ---- masks + passthrough: m1, m2, x1, x2 -----------------------------------
extern "C" __global__ void __launch_bounds__(256) tail_kernel(
    const float* __restrict__ x1, const float* __restrict__ x2,
    float* __restrict__ out)
{
    size_t i = (size_t)blockIdx.x * 256 + threadIdx.x;
    if (i >= S2) return;
    float a = x1[i], c = x2[i];
    const size_t base = 2 * S1 + 2 * S2;
    out[base + i]          = (a != 0.f) ? 1.f : 0.f;
    out[base + S2 + i]     = (c != 0.f) ? 1.f : 0.f;
    out[base + 2 * S2 + i] = a;
    out[base + 3 * S2 + i] = c;
}

extern "C" void kernel_launch(void* const* d_in, const int* in_sizes, int n_in,
                              void* d_out, int out_size, void* d_ws, size_t ws_size,
                              hipStream_t stream)
{
    (void)in_sizes; (void)n_in; (void)ws_size; (void)out_size;
    const float* x1   = (const float*)d_in[0];
    const float* x2   = (const float*)d_in[1];
    const float* X1   = (const float*)d_in[2];
    const float* X2   = (const float*)d_in[3];
    const float* w_in = (const float*)d_in[5];
    const float* b_in = (const float*)d_in[6];
    const float* c01w = (const float*)d_in[7];
    const float* c01b = (const float*)d_in[8];
    const float* c02w = (const float*)d_in[9];
    const float* c02b = (const float*)d_in[10];
    const float* c1pw = (const float*)d_in[11];
    const float* c1pb = (const float*)d_in[12];
    const float* c11w = (const float*)d_in[13];
    const float* c11b = (const float*)d_in[14];
    const float* c12w = (const float*)d_in[15];
    const float* c12b = (const float*)d_in[16];
    const float* dwp  = (const float*)d_in[17];
    const float* dbp  = (const float*)d_in[18];
    const float* pwp  = (const float*)d_in[19];
    const float* pbp  = (const float*)d_in[20];
    const float* fcw  = (const float*)d_in[21];
    const float* fcb  = (const float*)d_in[22];
    const float* fcrw = (const float*)d_in[29];
    const float* fcrb = (const float*)d_in[30];
    float* out = (float*)d_out;
    __hip_bfloat16* ws = (__hip_bfloat16*)d_ws;

    prep_w<<<824, 256, 0, stream>>>(c01w, c02w, c11w, c12w, c1pw, dwp, pwp,
                                    fcw, fcb, fcrw, fcrb, ws);

    fused_main<<<3 * BB * NTILE, 256, 0, stream>>>(
        x1, X1, X2, w_in, b_in, c01b, c02b, c1pb, c11b, c12b,
        dbp, pbp, ws, out);

    tail_kernel<<<(int)((S2 + 255) / 256), 256, 0, stream>>>(x1, x2, out);
}

// Round 9
// 818.273 us; speedup vs baseline: 1.5418x; 1.0242x over previous
//
#include <hip/hip_runtime.h>
#include <hip/hip_bf16.h>
#include <math.h>

// ---------------------------------------------------------------------------
// TSRL fused forward, MFMA edition (round 13: minimal-diff spill fix).
// r11/r12 both died on container acquisition ("failed twice") with no kernel
// evidence; this round shrinks the diff from the last-known-good r10 (636us
// fused, but spilled) to ONE region:
//  * L4 (the ~260-reg region that spilled in r10): single in-body A-fragment
//    (a[4], -16 arch regs; LDS latency covered by 20-MFMA chain + TLP) +
//    period-3 depth-2 B rotation (global latency needs the distance).
//  * pass-2 dense: EXACTLY r10's depth-1 ping-pong (ran fine, not binding).
//  * Everything else = r10: TT=64, swizzled C/Rr (byte^=(row&7)<<4), A
//    trimmed to 74 rows, XI/Gm/F2 static-disjoint, (256,2).
// Masking per round 6: L1 m<74, L2 m<72, L3 m<68, L4 exact 64.
// Tripwire: WRITE ~170MB / FETCH ~26-35MB. If WRITE>220MB => still spilling.
// ---------------------------------------------------------------------------

#define BB    128
#define TSEQ  512
#define NTILE 8
#define DIN   12
#define C0    64
#define C1    320
#define TT    64
#define PP    76
#define HALO  6
#define R64P  72      // bf16 elems/row (144B = 36 dw == 4 mod 32)

#define S1 ((size_t)BB * TSEQ * C1)
#define S2 ((size_t)BB * TSEQ * DIN)

typedef __attribute__((ext_vector_type(8))) __bf16 bf16x8;
typedef __attribute__((ext_vector_type(4))) float f32x4;
#define MFMA16(a, b, c) __builtin_amdgcn_mfma_f32_16x16x32_bf16(a, b, c, 0, 0, 0)

// workspace (bf16 elem offsets): transposed bf16 weights Bt[n][k]
#define O01 0         // c01wT [64][192]
#define O02 12288     // c02wT [64][192]
#define O11 24576     // c11wT [320][192]
#define O12 86016     // c12wT [320][1024]  (k<960: conv taps; k>=960: c1_p 1x1)
#define OD  413696    // dwT   [1280][320]
#define OP  823296    // pwT   [16][1280]   (rows 12..15 zero)
#define NWS 843776    // weight elems
#define OGM 843776    // Gm fp32 [12][12] (288 bf16 elems)
#define OF2 844064    // F2 fp32 [12]     (24 elems)

// LDS byte offsets (57872 total => 2 blocks/CU)
#define LA  0         // A: h0 raw -> h_b0 raw (T1)   [74][R64P] 10656
#define LB  10656     // Bf: gelu chain               [76][R64P] 10944 -> 21600
#define LC  10656     // C (TB1) overlays Bf post-L3  [68][640B]sw -> ends 54176
#define LXI 54176     // x_interp fp32 [64][12] 3072 -> 57248 (disjoint from C)
#define LGM 57248     // fc_w@fcr_w    [12][12] 576  -> 57824
#define LF2 57824     // fused bias    [12]     48   -> 57872
#define LSZ 57872
// pass-2 aliases (dead regions only):
#define LRR 0         // enc-out [64][640B]sw = 40960 (A,Bf,C dead)
#define LZB 40960     // per-wave z chunk [16][R64P] bf16 = 2304 x 4 -> 50176

__device__ __forceinline__ float bf2f(const __hip_bfloat16 v) { return __bfloat162float(v); }
__device__ __forceinline__ __hip_bfloat16 f2bf(float f)       { return __float2bfloat16(f); }
__device__ __forceinline__ float geluf(float x) {
    return 0.5f * x * (1.0f + erff(x * 0.7071067811865475f));
}
__device__ __forceinline__ bf16x8 ldb8(const void* p) { return *(const bf16x8*)p; }
// XOR-swizzled [row][320] bf16 tile: byte = (row*640 + col*2) ^ ((row&7)<<4).
// 640 % 128 == 0 -> each row 128-aligned; XOR of bits 4..6 stays in-row,
// bijective, keeps 16B alignment; rows r..r+7 spread across 8 16B slots.
__device__ __forceinline__ void* swp(void* base, int row, int col) {
    return (void*)((unsigned char*)base + ((row * 640 + col * 2) ^ ((row & 7) << 4)));
}

// ---- weight prep: fp32 -> bf16 transposed + Gm/F2, every launch ------------
extern "C" __global__ void __launch_bounds__(256) prep_w(
    const float* __restrict__ c01w, const float* __restrict__ c02w,
    const float* __restrict__ c11w, const float* __restrict__ c12w,
    const float* __restrict__ c1pw, const float* __restrict__ dw,
    const float* __restrict__ pw,
    const float* __restrict__ fcw,  const float* __restrict__ fcb,
    const float* __restrict__ fcrw, const float* __restrict__ fcrb,
    __hip_bfloat16* __restrict__ ws)
{
    for (size_t i = (size_t)blockIdx.x * 256 + threadIdx.x; i < NWS;
         i += (size_t)gridDim.x * 256) {
        float v;
        if (i < O02)      { int q = (int)i;        int n = q / 192, r = q % 192;
                            v = c01w[(n * 64 + (r & 63)) * 3 + (r >> 6)]; }
        else if (i < O11) { int q = (int)(i - O02); int n = q / 192, r = q % 192;
                            v = c02w[(n * 64 + (r & 63)) * 3 + (r >> 6)]; }
        else if (i < O12) { int q = (int)(i - O11); int n = q / 192, r = q % 192;
                            v = c11w[(n * 64 + (r & 63)) * 3 + (r >> 6)]; }
        else if (i < OD)  { int q = (int)(i - O12); int n = q >> 10, k = q & 1023;
                            v = (k < 960) ? c12w[(n * 320 + (k % 320)) * 3 + (k / 320)]
                                          : c1pw[n * 64 + (k - 960)]; }
        else if (i < OP)  { int q = (int)(i - OD);  int h = q / 320, c = q % 320;
                            v = dw[c * 1280 + h]; }
        else              { int q = (int)(i - OP);  int j = q / 1280, h = q % 1280;
                            v = (j < 12) ? pw[h * 12 + j] : 0.f; }
        ws[i] = f2bf(v);
    }
    if (blockIdx.x == 0) {
        float* gm = (float*)(ws + OGM);
        float* f2 = (float*)(ws + OF2);
        for (int o = threadIdx.x; o < 144; o += 256) {
            int j = o / 12, j2 = o - j * 12;
            float s = 0.f;
            for (int c = 0; c < C1; c++) s += fcw[j * C1 + c] * fcrw[c * 12 + j2];
            gm[o] = s;
        }
        if (threadIdx.x < 12) {
            float s = fcrb[threadIdx.x];
            for (int c = 0; c < C1; c++) s += fcb[c] * fcrw[c * 12 + threadIdx.x];
            f2[threadIdx.x] = s;
        }
    }
}

extern "C" __global__ void __launch_bounds__(256, 2) fused_main(
    const float* __restrict__ x1,  const float* __restrict__ X1,
    const float* __restrict__ X2,
    const float* __restrict__ w_in, const float* __restrict__ b_in,
    const float* __restrict__ c01b, const float* __restrict__ c02b,
    const float* __restrict__ c1pb, const float* __restrict__ c11b,
    const float* __restrict__ c12b,
    const float* __restrict__ db,   const float* __restrict__ pb,
    const __hip_bfloat16* __restrict__ ws,
    float* __restrict__ out)
{
    __shared__ __align__(16) unsigned char smem[LSZ];
    __hip_bfloat16* A  = (__hip_bfloat16*)(smem + LA);   // h0 -> T1, 74 rows
    __hip_bfloat16* Bf = (__hip_bfloat16*)(smem + LB);   // G0 -> T0 -> GH, 76 rows
    unsigned char*  Cb = smem + LC;                      // TB1 [68][320]sw
    unsigned char*  Rb = smem + LRR;                     // enc-out [64][320]sw
    float* XI = (float*)(smem + LXI);
    float* Gm = (float*)(smem + LGM);
    float* F2 = (float*)(smem + LF2);

    const int tid  = threadIdx.x;
    const int wv   = tid >> 6;
    const int lane = tid & 63;
    const int lm   = lane & 15;        // MFMA: A row / B col / D col
    const int lq   = lane >> 4;        // MFMA: k-octet / D row-quad
    const int bid  = blockIdx.x;
    const int pass = bid % 3;          // interleave heavy pass-2 blocks
    const int rem  = bid / 3;
    const int b    = rem >> 3;
    const int t0   = (rem & (NTILE - 1)) * TT;
    const float* xin = (pass == 0) ? X1 : (pass == 1) ? X2 : x1;

    const f32x4 Z4 = {0.f, 0.f, 0.f, 0.f};

    // ---- pass-2 prep: load Gm/F2 from ws, XI = ih_proj_b (region disjoint) -
    if (pass == 2) {
        const float* gmw = (const float*)(ws + OGM);
        const float* f2w = (const float*)(ws + OF2);
        for (int o = tid; o < 144; o += 256) Gm[o] = gmw[o];
        if (tid < 12) F2[tid] = f2w[tid];
        for (int o = tid; o < TT * 12; o += 256) XI[o] = pb[o % 12];
    }

    // ---- L0: x@w_in + b_in, rows [0,76) ------------------------------------
    for (int o = tid; o < PP * C0; o += 256) {
        int p = o >> 6, c = o & 63;
        int t = t0 + p - HALO;
        float acc = 0.f;
        if (t >= 0 && t < TSEQ) {
            acc = b_in[c];
            const float4* xr4 = (const float4*)(xin + ((size_t)b * TSEQ + t) * DIN);
            float4 v0 = xr4[0], v1 = xr4[1], v2 = xr4[2];
            const float xv[12] = {v0.x, v0.y, v0.z, v0.w, v1.x, v1.y,
                                  v1.z, v1.w, v2.x, v2.y, v2.z, v2.w};
            #pragma unroll
            for (int i = 0; i < DIN; i++) acc += xv[i] * w_in[i * C0 + c];
        }
        if (p < 74) A[p * R64P + c] = f2bf(acc);   // A rows 74/75 never read
        Bf[p * R64P + c] = f2bf(geluf(acc));
    }
    __syncthreads();

    // ---- L1: conv0_1 64->64 k3 d1 on gelu(h0)=Bf, out rows [1,75) ----------
    {
        const int oc = wv * 16 + lm;
        bf16x8 bw[6];
        #pragma unroll
        for (int ks = 0; ks < 6; ks++)
            bw[ks] = ldb8(ws + O01 + oc * 192 + ks * 32 + (lq << 3));
        f32x4 acc[5] = {Z4, Z4, Z4, Z4, Z4};
        #pragma unroll
        for (int ks = 0; ks < 6; ks++) {
            int tap = ks >> 1, ci = ((ks & 1) << 5) + (lq << 3);
            #pragma unroll
            for (int mt = 0; mt < 5; mt++) {
                int p = 1 + mt * 16 + lm + tap - 1; p = p > 75 ? 75 : p;
                acc[mt] = MFMA16(ldb8(Bf + p * R64P + ci), bw[ks], acc[mt]);
            }
        }
        __syncthreads();   // all waves done reading G0 before in-place write
        float bias = c01b[oc];
        #pragma unroll
        for (int mt = 0; mt < 5; mt++)
            #pragma unroll
            for (int r = 0; r < 4; r++) {
                int m = mt * 16 + lq * 4 + r;
                if (m < 74) {
                    int p = 1 + m, t = t0 + p - HALO;
                    Bf[p * R64P + oc] =
                        f2bf((t >= 0 && t < TSEQ) ? geluf(acc[mt][r] + bias) : 0.f);
                }
            }
    }
    __syncthreads();

    // ---- L2: conv0_2 on T0=Bf + residual h0=A, out rows [2,74) -------------
    {
        const int oc = wv * 16 + lm;
        bf16x8 bw[6];
        #pragma unroll
        for (int ks = 0; ks < 6; ks++)
            bw[ks] = ldb8(ws + O02 + oc * 192 + ks * 32 + (lq << 3));
        f32x4 acc[5] = {Z4, Z4, Z4, Z4, Z4};
        #pragma unroll
        for (int ks = 0; ks < 6; ks++) {
            int tap = ks >> 1, ci = ((ks & 1) << 5) + (lq << 3);
            #pragma unroll
            for (int mt = 0; mt < 5; mt++) {
                int p = 2 + mt * 16 + lm + tap - 1; p = p > 75 ? 75 : p;
                acc[mt] = MFMA16(ldb8(Bf + p * R64P + ci), bw[ks], acc[mt]);
            }
        }
        float resv[5][4];
        #pragma unroll
        for (int mt = 0; mt < 5; mt++)
            #pragma unroll
            for (int r = 0; r < 4; r++) {
                int m = mt * 16 + lq * 4 + r;
                resv[mt][r] = (m < 72) ? bf2f(A[(2 + m) * R64P + oc]) : 0.f;
            }
        __syncthreads();   // reads of Bf and A complete
        float bias = c02b[oc];
        #pragma unroll
        for (int mt = 0; mt < 5; mt++)
            #pragma unroll
            for (int r = 0; r < 4; r++) {
                int m = mt * 16 + lq * 4 + r;
                if (m < 72) {
                    int p = 2 + m, t = t0 + p - HALO;
                    bool v = (t >= 0 && t < TSEQ);
                    float hb = acc[mt][r] + bias + resv[mt][r];
                    A [p * R64P + oc] = f2bf(v ? hb : 0.f);          // T1 raw
                    Bf[p * R64P + oc] = f2bf(v ? geluf(hb) : 0.f);   // GH
                }
            }
    }
    __syncthreads();

    // ---- L3: c1_1 64->320 k3 d2 on GH=Bf, out rows [4,72) -> C[m<68] -------
    // B ping-pong depth-1 (r6-proven); A in-phase.
    {
        f32x4 acc[5][5];
        #pragma unroll
        for (int mt = 0; mt < 5; mt++)
            #pragma unroll
            for (int nt = 0; nt < 5; nt++) acc[mt][nt] = Z4;
        bf16x8 bcur[5], bnxt[5];
        #pragma unroll
        for (int nt = 0; nt < 5; nt++)
            bcur[nt] = ldb8(ws + O11 + (wv * 80 + nt * 16 + lm) * 192 + (lq << 3));
        #pragma unroll
        for (int ks = 0; ks < 6; ks++) {
            if (ks < 5)
                #pragma unroll
                for (int nt = 0; nt < 5; nt++)
                    bnxt[nt] = ldb8(ws + O11 + (wv * 80 + nt * 16 + lm) * 192
                                    + (ks + 1) * 32 + (lq << 3));
            int tap = ks >> 1, ci = ((ks & 1) << 5) + (lq << 3);
            bf16x8 a[5];
            #pragma unroll
            for (int mt = 0; mt < 5; mt++) {
                int p = 4 + mt * 16 + lm + 2 * (tap - 1); p = p > 75 ? 75 : p;
                a[mt] = ldb8(Bf + p * R64P + ci);
            }
            #pragma unroll
            for (int nt = 0; nt < 5; nt++)
                #pragma unroll
                for (int mt = 0; mt < 5; mt++)
                    acc[mt][nt] = MFMA16(a[mt], bcur[nt], acc[mt][nt]);
            #pragma unroll
            for (int nt = 0; nt < 5; nt++) bcur[nt] = bnxt[nt];
        }
        __syncthreads();   // all waves done reading Bf before C overlays it
        #pragma unroll
        for (int nt = 0; nt < 5; nt++) {
            int oc = wv * 80 + nt * 16 + lm;
            float bias = c11b[oc];
            #pragma unroll
            for (int mt = 0; mt < 5; mt++)
                #pragma unroll
                for (int r = 0; r < 4; r++) {
                    int m = mt * 16 + lq * 4 + r;
                    if (m < 68) {
                        int t = t0 + 4 + m - HALO;
                        *(__hip_bfloat16*)swp(Cb, m, oc) =
                            f2bf((t >= 0 && t < TSEQ) ? geluf(acc[mt][nt][r] + bias) : 0.f);
                    }
                }
        }
    }
    __syncthreads();

    // ---- L4: c1_2 320->320 k3 d2 (K=960) + c1_p 1x1 on T1=A (K=64) ---------
    // out rows [6,70) == 64 exactly. B depth-2 (period-3 rotation, 5x6
    // statically-named phases), single in-body A (LDS; covered by MFMA+TLP).
    {
        f32x4 acc[4][5];
        #pragma unroll
        for (int mt = 0; mt < 4; mt++)
            #pragma unroll
            for (int nt = 0; nt < 5; nt++) acc[mt][nt] = Z4;
        bf16x8 a[4], b0[5], b1[5], b2[5];
        auto LDA = [&](int ks, bf16x8 (&aa)[4]) {
            if (ks < 30) {
                int tap = (ks >= 20) ? 2 : (ks >= 10 ? 1 : 0);
                int ci = (ks - tap * 10) * 32 + (lq << 3);
                #pragma unroll
                for (int mt = 0; mt < 4; mt++)
                    aa[mt] = ldb8(swp(Cb, 2 + mt * 16 + lm + 2 * (tap - 1), ci));
            } else {
                int ci = ((ks - 30) << 5) + (lq << 3);
                #pragma unroll
                for (int mt = 0; mt < 4; mt++)
                    aa[mt] = ldb8(A + (6 + mt * 16 + lm) * R64P + ci);
            }
        };
        auto LDB = [&](int ks, bf16x8 (&bw)[5]) {
            #pragma unroll
            for (int nt = 0; nt < 5; nt++)
                bw[nt] = ldb8(ws + O12 + (wv * 80 + nt * 16 + lm) * 1024
                              + ks * 32 + (lq << 3));
        };
        auto FMA = [&](bf16x8 (&aa)[4], bf16x8 (&bw)[5]) {
            #pragma unroll
            for (int nt = 0; nt < 5; nt++)
                #pragma unroll
                for (int mt = 0; mt < 4; mt++)
                    acc[mt][nt] = MFMA16(aa[mt], bw[nt], acc[mt][nt]);
        };
        LDB(0, b0); LDB(1, b1);
        for (int g = 0; g < 5; g++) {
            int p = 6 * g;
            LDB(p + 2, b2); LDA(p + 0, a); FMA(a, b0);
            LDB(p + 3, b0); LDA(p + 1, a); FMA(a, b1);
            LDB(p + 4, b1); LDA(p + 2, a); FMA(a, b2);
            LDB(p + 5, b2); LDA(p + 3, a); FMA(a, b0);
            LDB(p + 6, b0); LDA(p + 4, a); FMA(a, b1);
            LDB(p + 7, b1); LDA(p + 5, a); FMA(a, b2);
        }
        // phases 30,31 (T1): b0=B(30), b1=B(31) already resident
        LDA(30, a); FMA(a, b0);
        LDA(31, a); FMA(a, b1);

        if (pass < 2) {
            #pragma unroll
            for (int nt = 0; nt < 5; nt++) {
                int oc = wv * 80 + nt * 16 + lm;
                float bias = c12b[oc] + c1pb[oc];
                const size_t obase = (pass == 1) ? S1 : (size_t)0;
                #pragma unroll
                for (int mt = 0; mt < 4; mt++)
                    #pragma unroll
                    for (int r = 0; r < 4; r++) {
                        int m = mt * 16 + lq * 4 + r;
                        out[obase + ((size_t)b * TSEQ + t0 + m) * C1 + oc] =
                            acc[mt][nt][r] + bias;
                    }
            }
        } else {
            __syncthreads();   // all waves done reading C,A -> safe to alias
            #pragma unroll
            for (int nt = 0; nt < 5; nt++) {
                int oc = wv * 80 + nt * 16 + lm;
                float bias = c12b[oc] + c1pb[oc];
                #pragma unroll
                for (int mt = 0; mt < 4; mt++)
                    #pragma unroll
                    for (int r = 0; r < 4; r++) {
                        int m = mt * 16 + lq * 4 + r;
                        *(__hip_bfloat16*)swp(Rb, m, oc) = f2bf(acc[mt][nt][r] + bias);
                    }
            }
            __syncthreads();   // Rr complete (cross-wave K in dense stage)
        }
    }

    // ---- pass-2: dense 320->1280, relu, @pw (MFMA), @Gm, outputs -----------
    // (exactly the r10 depth-1 ping-pong form, which ran cleanly)
    if (pass == 2) {
        __hip_bfloat16* zb = (__hip_bfloat16*)(smem + LZB) + wv * (16 * R64P);
        f32x4 xacc[4] = {Z4, Z4, Z4, Z4};
        for (int cn = 0; cn < 5; cn++) {
            const int h0 = wv * 320 + cn * 64;
            f32x4 dacc[4][4];
            #pragma unroll
            for (int mt = 0; mt < 4; mt++)
                #pragma unroll
                for (int nt = 0; nt < 4; nt++) dacc[mt][nt] = Z4;
            bf16x8 ba[4], bb[4];
            #pragma unroll
            for (int nt = 0; nt < 4; nt++)
                ba[nt] = ldb8(ws + OD + (h0 + nt * 16 + lm) * 320 + (lq << 3));
            for (int ks = 0; ks < 10; ks += 2) {
                #pragma unroll
                for (int nt = 0; nt < 4; nt++)
                    bb[nt] = ldb8(ws + OD + (h0 + nt * 16 + lm) * 320
                                  + (ks + 1) * 32 + (lq << 3));
                {
                    bf16x8 a[4];
                    #pragma unroll
                    for (int mt = 0; mt < 4; mt++)
                        a[mt] = ldb8(swp(Rb, mt * 16 + lm, ks * 32 + (lq << 3)));
                    #pragma unroll
                    for (int nt = 0; nt < 4; nt++)
                        #pragma unroll
                        for (int mt = 0; mt < 4; mt++)
                            dacc[mt][nt] = MFMA16(a[mt], ba[nt], dacc[mt][nt]);
                }
                if (ks + 2 < 10)
                    #pragma unroll
                    for (int nt = 0; nt < 4; nt++)
                        ba[nt] = ldb8(ws + OD + (h0 + nt * 16 + lm) * 320
                                      + (ks + 2) * 32 + (lq << 3));
                {
                    bf16x8 a[4];
                    #pragma unroll
                    for (int mt = 0; mt < 4; mt++)
                        a[mt] = ldb8(swp(Rb, mt * 16 + lm, (ks + 1) * 32 + (lq << 3)));
                    #pragma unroll
                    for (int nt = 0; nt < 4; nt++)
                        #pragma unroll
                        for (int mt = 0; mt < 4; mt++)
                            dacc[mt][nt] = MFMA16(a[mt], bb[nt], dacc[mt][nt]);
                }
            }
            // per-mt: relu -> zb (wave-private, DS in-order) -> proj MFMA
            #pragma unroll
            for (int mt = 0; mt < 4; mt++) {
                #pragma unroll
                for (int nt = 0; nt < 4; nt++) {
                    int h = h0 + nt * 16 + lm;
                    float dbv = db[h];
                    #pragma unroll
                    for (int r = 0; r < 4; r++)
                        zb[(lq * 4 + r) * R64P + nt * 16 + lm] =
                            f2bf(fmaxf(dacc[mt][nt][r] + dbv, 0.f));
                }
                #pragma unroll
                for (int k2 = 0; k2 < 2; k2++) {
                    int hl = k2 * 32 + (lq << 3);
                    bf16x8 bf = ldb8(ws + OP + lm * 1280 + h0 + hl);
                    xacc[mt] = MFMA16(ldb8(zb + lm * R64P + hl), bf, xacc[mt]);
                }
            }
        }
        if (lm < 12) {
            #pragma unroll
            for (int mt = 0; mt < 4; mt++)
                #pragma unroll
                for (int r = 0; r < 4; r++)
                    atomicAdd(&XI[(mt * 16 + lq * 4 + r) * 12 + lm], xacc[mt][r]);
        }
        __syncthreads();
        for (int o = tid; o < TT * 12; o += 256) {
            int p = o / 12, j2 = o - p * 12;
            float val = F2[j2];
            #pragma unroll
            for (int j = 0; j < 12; j++) val += XI[p * 12 + j] * Gm[j * 12 + j2];
            size_t idx = ((size_t)b * TSEQ + t0 + p) * DIN + j2;
            out[2 * S1 + idx]      = val;   // outputs1
            out[2 * S1 + S2 + idx] = val;   // outputs2 (ref uses y_t1 for both)
        }
    }
}

// ---- masks + passthrough: m1, m2, x1, x2 -----------------------------------
extern "C" __global__ void __launch_bounds__(256) tail_kernel(
    const float* __restrict__ x1, const float* __restrict__ x2,
    float* __restrict__ out)
{
    size_t i = (size_t)blockIdx.x * 256 + threadIdx.x;
    if (i >= S2) return;
    float a = x1[i], c = x2[i];
    const size_t base = 2 * S1 + 2 * S2;
    out[base + i]          = (a != 0.f) ? 1.f : 0.f;
    out[base + S2 + i]     = (c != 0.f) ? 1.f : 0.f;
    out[base + 2 * S2 + i] = a;
    out[base + 3 * S2 + i] = c;
}

extern "C" void kernel_launch(void* const* d_in, const int* in_sizes, int n_in,
                              void* d_out, int out_size, void* d_ws, size_t ws_size,
                              hipStream_t stream)
{
    (void)in_sizes; (void)n_in; (void)ws_size; (void)out_size;
    const float* x1   = (const float*)d_in[0];
    const float* x2   = (const float*)d_in[1];
    const float* X1   = (const float*)d_in[2];
    const float* X2   = (const float*)d_in[3];
    const float* w_in = (const float*)d_in[5];
    const float* b_in = (const float*)d_in[6];
    const float* c01w = (const float*)d_in[7];
    const float* c01b = (const float*)d_in[8];
    const float* c02w = (const float*)d_in[9];
    const float* c02b = (const float*)d_in[10];
    const float* c1pw = (const float*)d_in[11];
    const float* c1pb = (const float*)d_in[12];
    const float* c11w = (const float*)d_in[13];
    const float* c11b = (const float*)d_in[14];
    const float* c12w = (const float*)d_in[15];
    const float* c12b = (const float*)d_in[16];
    const float* dwp  = (const float*)d_in[17];
    const float* dbp  = (const float*)d_in[18];
    const float* pwp  = (const float*)d_in[19];
    const float* pbp  = (const float*)d_in[20];
    const float* fcw  = (const float*)d_in[21];
    const float* fcb  = (const float*)d_in[22];
    const float* fcrw = (const float*)d_in[29];
    const float* fcrb = (const float*)d_in[30];
    float* out = (float*)d_out;
    __hip_bfloat16* ws = (__hip_bfloat16*)d_ws;

    prep_w<<<824, 256, 0, stream>>>(c01w, c02w, c11w, c12w, c1pw, dwp, pwp,
                                    fcw, fcb, fcrw, fcrb, ws);

    fused_main<<<3 * BB * NTILE, 256, 0, stream>>>(
        x1, X1, X2, w_in, b_in, c01b, c02b, c1pb, c11b, c12b,
        dbp, pbp, ws, out);

    tail_kernel<<<(int)((S2 + 255) / 256), 256, 0, stream>>>(x1, x2, out);
}